// Round 1
// baseline (434.662 us; speedup 1.0000x reference)
//
#include <hip/hip_runtime.h>

// InteractionBlock (ViT-Adapter injector+extractor with MSDeformAttn) for MI355X.
// Pipeline: weight transpose/cast -> LN -> bf16 MFMA GEMMs -> deform sampler ->
// residual -> LN -> GEMMs -> sampler -> GEMM -> add+LN.

#define LQ_VIT 2304
#define NA_ADA 12096

typedef float f32x4 __attribute__((ext_vector_type(4)));
typedef short bf16x8 __attribute__((ext_vector_type(8)));

__device__ __forceinline__ unsigned short f2bf(float f) {
  unsigned u = __builtin_bit_cast(unsigned, f);
  u += 0x7FFFu + ((u >> 16) & 1u);   // round-to-nearest-even bf16
  return (unsigned short)(u >> 16);
}

__device__ __forceinline__ void gload_lds16(const void* g, void* l) {
  __builtin_amdgcn_global_load_lds(
      (__attribute__((address_space(1))) void*)(void*)g,
      (__attribute__((address_space(3))) void*)l, 16, 0, 0);
}

// ---------------- weight transpose + bf16 cast: W[K,N] f32 -> WT[N,K] bf16 ----
__global__ __launch_bounds__(256) void transpose_cast_kernel(
    const float* __restrict__ W, unsigned short* __restrict__ WT, int K, int N) {
  __shared__ float tile[32][33];
  int kb = blockIdx.x * 32, nb = blockIdx.y * 32;
  int tx = threadIdx.x, ty = threadIdx.y;  // blockDim = (32, 8)
  for (int i = ty; i < 32; i += 8) {
    int k = kb + i, n = nb + tx;
    tile[i][tx] = (k < K && n < N) ? W[(size_t)k * N + n] : 0.f;
  }
  __syncthreads();
  for (int i = ty; i < 32; i += 8) {
    int n = nb + i, k = kb + tx;
    if (n < N && k < K) WT[(size_t)n * K + k] = f2bf(tile[tx][i]);
  }
}

// ---------------- f32 -> bf16 cast (vectorized, n4 = count/4) ----------------
__global__ __launch_bounds__(256) void cast_bf16_kernel(
    const float* __restrict__ in, unsigned short* __restrict__ out, int n4) {
  int i = blockIdx.x * 256 + threadIdx.x;
  if (i < n4) {
    float4 v = ((const float4*)in)[i];
    ushort4 o;
    o.x = f2bf(v.x); o.y = f2bf(v.y); o.z = f2bf(v.z); o.w = f2bf(v.w);
    ((ushort4*)out)[i] = o;
  }
}

// ---------------- LayerNorm (row=768) -> bf16 out; one wave per row ----------
__global__ __launch_bounds__(256) void ln_bf16_kernel(
    const float* __restrict__ X, const float* __restrict__ g,
    const float* __restrict__ b, unsigned short* __restrict__ out, int R) {
  int wid = blockIdx.x * 4 + (threadIdx.x >> 6);
  int lane = threadIdx.x & 63;
  if (wid >= R) return;
  const float* row = X + (size_t)wid * 768;
  float x[12]; float s = 0.f;
#pragma unroll
  for (int j = 0; j < 12; j++) { x[j] = row[lane + j * 64]; s += x[j]; }
#pragma unroll
  for (int o = 32; o >= 1; o >>= 1) s += __shfl_xor(s, o);
  float mean = s * (1.f / 768.f);
  float v = 0.f;
#pragma unroll
  for (int j = 0; j < 12; j++) { float d = x[j] - mean; v += d * d; }
#pragma unroll
  for (int o = 32; o >= 1; o >>= 1) v += __shfl_xor(v, o);
  float rs = rsqrtf(v * (1.f / 768.f) + 1e-6f);
#pragma unroll
  for (int j = 0; j < 12; j++) {
    int c = lane + j * 64;
    out[(size_t)wid * 768 + c] = f2bf((x[j] - mean) * rs * g[c] + b[c]);
  }
}

// ---------------- add + LayerNorm -> f32 out; one wave per row ---------------
__global__ __launch_bounds__(256) void add_ln_f32_kernel(
    const float* __restrict__ Xa, const float* __restrict__ Xb,
    const float* __restrict__ g, const float* __restrict__ b,
    float* __restrict__ out, int R) {
  int wid = blockIdx.x * 4 + (threadIdx.x >> 6);
  int lane = threadIdx.x & 63;
  if (wid >= R) return;
  const float* ra = Xa + (size_t)wid * 768;
  const float* rb = Xb + (size_t)wid * 768;
  float x[12]; float s = 0.f;
#pragma unroll
  for (int j = 0; j < 12; j++) { x[j] = ra[lane + j * 64] + rb[lane + j * 64]; s += x[j]; }
#pragma unroll
  for (int o = 32; o >= 1; o >>= 1) s += __shfl_xor(s, o);
  float mean = s * (1.f / 768.f);
  float v = 0.f;
#pragma unroll
  for (int j = 0; j < 12; j++) { float d = x[j] - mean; v += d * d; }
#pragma unroll
  for (int o = 32; o >= 1; o >>= 1) v += __shfl_xor(v, o);
  float rs = rsqrtf(v * (1.f / 768.f) + 1e-6f);
#pragma unroll
  for (int j = 0; j < 12; j++) {
    int c = lane + j * 64;
    out[(size_t)wid * 768 + c] = (x[j] - mean) * rs * g[c] + b[c];
  }
}

// ---------------- residual: q2 = vit + gamma*attn; also write vit_out --------
__global__ __launch_bounds__(768) void residual_kernel(
    const float* __restrict__ vit, const float* __restrict__ attn,
    const float* __restrict__ gamma, float* __restrict__ q2,
    float* __restrict__ vout) {
  int i = blockIdx.x * 768 + threadIdx.x;
  float val = vit[i] + gamma[threadIdx.x] * attn[i];
  q2[i] = val; vout[i] = val;
}

// ---------------- bf16 MFMA GEMM: C[M,N] f32 = A[M,K]bf16 @ BT[N,K]bf16^T + bias
// m97 structure: 128x128 tile, BK=64, 4 waves (2x2), each 4x4 frags of 16x16x32.
__global__ __launch_bounds__(256) void gemm_bf16_kernel(
    const unsigned short* __restrict__ A, const unsigned short* __restrict__ BT,
    const float* __restrict__ bias, float* __restrict__ C, int M, int N, int K) {
  const int BK = 64;
  __shared__ unsigned short As[128 * BK];  // [128][64] row-major
  __shared__ unsigned short Bs[128 * BK];
  int m0 = blockIdx.x * 128, n0 = blockIdx.y * 128;
  int tid = threadIdx.x;
  int w = tid >> 6, lane = tid & 63;
  int wr = w >> 1, wc = w & 1;
  int frow = lane & 15, fk = (lane >> 4) * 8;
  int sr = lane >> 3;          // staging row within 8-row chunk
  int sk = (lane & 7) * 8;     // staging k-element offset
  f32x4 acc[4][4] = {};
  int kTiles = K / BK;
  for (int kt = 0; kt < kTiles; kt++) {
    int k0 = kt * BK;
    __syncthreads();  // protect LDS from previous iter's readers
#pragma unroll
    for (int i = 0; i < 4; i++) {
      int ch = w * 4 + i;                    // 16 chunks x 1024B = 16KB tile
      int row = ch * 8 + sr;
      int gm = m0 + row; if (gm >= M) gm = M - 1;
      int gn = n0 + row; if (gn >= N) gn = N - 1;
      gload_lds16(&A[(size_t)gm * K + k0 + sk], &As[ch * 512]);
      gload_lds16(&BT[(size_t)gn * K + k0 + sk], &Bs[ch * 512]);
    }
    __syncthreads();  // drains vmcnt: tiles ready
#pragma unroll
    for (int kk = 0; kk < BK; kk += 32) {
      bf16x8 af[4], bfr[4];
#pragma unroll
      for (int m = 0; m < 4; m++)
        af[m] = *(const bf16x8*)&As[(wr * 64 + m * 16 + frow) * BK + kk + fk];
#pragma unroll
      for (int n = 0; n < 4; n++)
        bfr[n] = *(const bf16x8*)&Bs[(wc * 64 + n * 16 + frow) * BK + kk + fk];
#pragma unroll
      for (int m = 0; m < 4; m++)
#pragma unroll
        for (int n = 0; n < 4; n++)
          acc[m][n] = __builtin_amdgcn_mfma_f32_16x16x32_bf16(af[m], bfr[n], acc[m][n], 0, 0, 0);
    }
  }
  int orow = (lane >> 4) * 4, ocol = lane & 15;
#pragma unroll
  for (int m = 0; m < 4; m++) {
    int gmb = m0 + wr * 64 + m * 16 + orow;
#pragma unroll
    for (int n = 0; n < 4; n++) {
      int gn = n0 + wc * 64 + n * 16 + ocol;
      if (gn < N) {
        float bv = bias[gn];
#pragma unroll
        for (int r = 0; r < 4; r++) {
          int gm = gmb + r;
          if (gm < M) C[(size_t)gm * N + gn] = acc[m][n][r] + bv;
        }
      }
    }
  }
}

// ---------------- deformable samplers ----------------------------------------
__device__ __forceinline__ void gather2(const float* __restrict__ v, int row,
                                        int c, float wgt, float& a0, float& a1) {
  const float2 val = *(const float2*)&v[(size_t)row * 768 + c];
  a0 += wgt * val.x; a1 += wgt * val.y;
}

// Injector: Lq=2304 queries, 6 heads, 3 levels {96,48,24}, 4 points.
__global__ __launch_bounds__(256) void sampler_inj_kernel(
    const float* __restrict__ ref, const float* __restrict__ offl,
    const float* __restrict__ awl, const float* __restrict__ v,
    unsigned short* __restrict__ out) {
  int gw = (blockIdx.x * 256 + threadIdx.x) >> 6;
  int lane = threadIdx.x & 63;
  int q = gw / 6, h = gw - q * 6;
  if (q >= LQ_VIT) return;
  float rx = ref[q * 2], ry = ref[q * 2 + 1];
  float lg[12]; float mx = -1e30f;
#pragma unroll
  for (int i = 0; i < 12; i++) { lg[i] = awl[q * 72 + h * 12 + i]; mx = fmaxf(mx, lg[i]); }
  float s = 0.f;
#pragma unroll
  for (int i = 0; i < 12; i++) { lg[i] = expf(lg[i] - mx); s += lg[i]; }
  float inv = 1.f / s;
  float a0 = 0.f, a1 = 0.f;
  int c = h * 128 + lane * 2;
  const int LW[3] = {96, 48, 24};
  const int LS[3] = {0, 9216, 11520};
#pragma unroll
  for (int l = 0; l < 3; l++) {
    const int Wl = LW[l], st = LS[l];
    const float Wf = (float)Wl;
#pragma unroll
    for (int p = 0; p < 4; p++) {
      float ox = offl[q * 144 + ((h * 3 + l) * 4 + p) * 2 + 0];
      float oy = offl[q * 144 + ((h * 3 + l) * 4 + p) * 2 + 1];
      float ix = (rx + ox / Wf) * Wf - 0.5f;
      float iy = (ry + oy / Wf) * Wf - 0.5f;
      float x0f = floorf(ix), y0f = floorf(iy);
      float wx = ix - x0f, wy = iy - y0f;
      int x0 = (int)x0f, y0 = (int)y0f;
      float aw = lg[l * 4 + p] * inv;
      float w00 = (1.f - wx) * (1.f - wy) * aw, w01 = wx * (1.f - wy) * aw;
      float w10 = (1.f - wx) * wy * aw,         w11 = wx * wy * aw;
      bool xv0 = (x0 >= 0) && (x0 < Wl), xv1 = (x0 + 1 >= 0) && (x0 + 1 < Wl);
      bool yv0 = (y0 >= 0) && (y0 < Wl), yv1 = (y0 + 1 >= 0) && (y0 + 1 < Wl);
      if (xv0 && yv0) gather2(v, st + y0 * Wl + x0,           c, w00, a0, a1);
      if (xv1 && yv0) gather2(v, st + y0 * Wl + x0 + 1,       c, w01, a0, a1);
      if (xv0 && yv1) gather2(v, st + (y0 + 1) * Wl + x0,     c, w10, a0, a1);
      if (xv1 && yv1) gather2(v, st + (y0 + 1) * Wl + x0 + 1, c, w11, a0, a1);
    }
  }
  ushort2 o2; o2.x = f2bf(a0); o2.y = f2bf(a1);
  *(ushort2*)&out[(size_t)q * 768 + c] = o2;
}

// Extractor: Lq=12096 queries, 6 heads, 1 level (48x48), 4 points.
__global__ __launch_bounds__(256) void sampler_ext_kernel(
    const float* __restrict__ ref, const float* __restrict__ offl,
    const float* __restrict__ awl, const float* __restrict__ v,
    unsigned short* __restrict__ out) {
  int gw = (blockIdx.x * 256 + threadIdx.x) >> 6;
  int lane = threadIdx.x & 63;
  int q = gw / 6, h = gw - q * 6;
  if (q >= NA_ADA) return;
  float rx = ref[q * 2], ry = ref[q * 2 + 1];
  float lg[4]; float mx = -1e30f;
#pragma unroll
  for (int p = 0; p < 4; p++) { lg[p] = awl[q * 24 + h * 4 + p]; mx = fmaxf(mx, lg[p]); }
  float s = 0.f;
#pragma unroll
  for (int p = 0; p < 4; p++) { lg[p] = expf(lg[p] - mx); s += lg[p]; }
  float inv = 1.f / s;
  float a0 = 0.f, a1 = 0.f;
  int c = h * 128 + lane * 2;
#pragma unroll
  for (int p = 0; p < 4; p++) {
    float ox = offl[q * 48 + (h * 4 + p) * 2 + 0];
    float oy = offl[q * 48 + (h * 4 + p) * 2 + 1];
    float ix = (rx + ox / 48.f) * 48.f - 0.5f;
    float iy = (ry + oy / 48.f) * 48.f - 0.5f;
    float x0f = floorf(ix), y0f = floorf(iy);
    float wx = ix - x0f, wy = iy - y0f;
    int x0 = (int)x0f, y0 = (int)y0f;
    float aw = lg[p] * inv;
    float w00 = (1.f - wx) * (1.f - wy) * aw, w01 = wx * (1.f - wy) * aw;
    float w10 = (1.f - wx) * wy * aw,         w11 = wx * wy * aw;
    bool xv0 = (x0 >= 0) && (x0 < 48), xv1 = (x0 + 1 >= 0) && (x0 + 1 < 48);
    bool yv0 = (y0 >= 0) && (y0 < 48), yv1 = (y0 + 1 >= 0) && (y0 + 1 < 48);
    if (xv0 && yv0) gather2(v, y0 * 48 + x0,           c, w00, a0, a1);
    if (xv1 && yv0) gather2(v, y0 * 48 + x0 + 1,       c, w01, a0, a1);
    if (xv0 && yv1) gather2(v, (y0 + 1) * 48 + x0,     c, w10, a0, a1);
    if (xv1 && yv1) gather2(v, (y0 + 1) * 48 + x0 + 1, c, w11, a0, a1);
  }
  ushort2 o2; o2.x = f2bf(a0); o2.y = f2bf(a1);
  *(ushort2*)&out[(size_t)q * 768 + c] = o2;
}

extern "C" void kernel_launch(void* const* d_in, const int* in_sizes, int n_in,
                              void* d_out, int out_size, void* d_ws, size_t ws_size,
                              hipStream_t stream) {
  (void)in_sizes; (void)n_in; (void)out_size; (void)ws_size;
  const float* vit      = (const float*)d_in[0];
  const float* adapter  = (const float*)d_in[1];
  const float* ref1     = (const float*)d_in[2];
  const float* ref2     = (const float*)d_in[3];
  const float* inj_qn_g = (const float*)d_in[4];
  const float* inj_qn_b = (const float*)d_in[5];
  const float* inj_Wv   = (const float*)d_in[6];
  const float* inj_bv   = (const float*)d_in[7];
  const float* inj_Ws   = (const float*)d_in[8];
  const float* inj_bs   = (const float*)d_in[9];
  const float* inj_Wa   = (const float*)d_in[10];
  const float* inj_ba   = (const float*)d_in[11];
  const float* inj_Wo   = (const float*)d_in[12];
  const float* inj_bo   = (const float*)d_in[13];
  const float* inj_gamma= (const float*)d_in[14];
  const float* ext_vn_g = (const float*)d_in[15];
  const float* ext_vn_b = (const float*)d_in[16];
  const float* ext_qn_g = (const float*)d_in[17];
  const float* ext_qn_b = (const float*)d_in[18];
  const float* ext_Wv   = (const float*)d_in[19];
  const float* ext_bv   = (const float*)d_in[20];
  const float* ext_Ws   = (const float*)d_in[21];
  const float* ext_bs   = (const float*)d_in[22];
  const float* ext_Wa   = (const float*)d_in[23];
  const float* ext_ba   = (const float*)d_in[24];
  const float* ext_Wo   = (const float*)d_in[25];
  const float* ext_bo   = (const float*)d_in[26];

  size_t cur = 0;
  auto take = [&](size_t bytes) {
    void* p = (char*)d_ws + cur;
    cur += (bytes + 255) & ~(size_t)255;
    return p;
  };
  unsigned short* WTIV = (unsigned short*)take((size_t)768 * 768 * 2);
  unsigned short* WTIO = (unsigned short*)take((size_t)768 * 768 * 2);
  unsigned short* WTEV = (unsigned short*)take((size_t)768 * 768 * 2);
  unsigned short* WTEO = (unsigned short*)take((size_t)768 * 768 * 2);
  unsigned short* WTIS = (unsigned short*)take((size_t)144 * 768 * 2);
  unsigned short* WTIA = (unsigned short*)take((size_t)72 * 768 * 2);
  unsigned short* WTES = (unsigned short*)take((size_t)48 * 768 * 2);
  unsigned short* WTEA = (unsigned short*)take((size_t)24 * 768 * 2);
  unsigned short* ADBF = (unsigned short*)take((size_t)NA_ADA * 768 * 2);
  unsigned short* QLN  = (unsigned short*)take((size_t)LQ_VIT * 768 * 2);
  float* VINJ  = (float*)take((size_t)NA_ADA * 768 * 4);
  float* OFFI  = (float*)take((size_t)LQ_VIT * 144 * 4);
  float* AWLI  = (float*)take((size_t)LQ_VIT * 72 * 4);
  unsigned short* SAMPI = (unsigned short*)take((size_t)LQ_VIT * 768 * 2);
  float* ATTNI = (float*)take((size_t)LQ_VIT * 768 * 4);
  float* Q2    = (float*)take((size_t)LQ_VIT * 768 * 4);
  unsigned short* VLN  = (unsigned short*)take((size_t)LQ_VIT * 768 * 2);
  float* VEXT  = (float*)take((size_t)LQ_VIT * 768 * 4);
  float* OFFE  = (float*)take((size_t)NA_ADA * 48 * 4);
  float* AWLE  = (float*)take((size_t)NA_ADA * 24 * 4);
  unsigned short* SAMPE = ADBF;  // adapter_bf16 dead after ext Ws/Wa GEMMs
  float* ATTN2 = VINJ;           // v_inj dead after injector sampling

  float* out_vit = (float*)d_out;
  float* out_ada = out_vit + (size_t)LQ_VIT * 768;

  dim3 tcb(32, 8);
  transpose_cast_kernel<<<dim3(24, 24), tcb, 0, stream>>>(inj_Wv, WTIV, 768, 768);
  transpose_cast_kernel<<<dim3(24, 24), tcb, 0, stream>>>(inj_Wo, WTIO, 768, 768);
  transpose_cast_kernel<<<dim3(24, 24), tcb, 0, stream>>>(ext_Wv, WTEV, 768, 768);
  transpose_cast_kernel<<<dim3(24, 24), tcb, 0, stream>>>(ext_Wo, WTEO, 768, 768);
  transpose_cast_kernel<<<dim3(24, 5),  tcb, 0, stream>>>(inj_Ws, WTIS, 768, 144);
  transpose_cast_kernel<<<dim3(24, 3),  tcb, 0, stream>>>(inj_Wa, WTIA, 768, 72);
  transpose_cast_kernel<<<dim3(24, 2),  tcb, 0, stream>>>(ext_Ws, WTES, 768, 48);
  transpose_cast_kernel<<<dim3(24, 1),  tcb, 0, stream>>>(ext_Wa, WTEA, 768, 24);

  cast_bf16_kernel<<<9072, 256, 0, stream>>>(adapter, ADBF, (NA_ADA * 768) / 4);
  ln_bf16_kernel<<<576, 256, 0, stream>>>(vit, inj_qn_g, inj_qn_b, QLN, LQ_VIT);

  gemm_bf16_kernel<<<dim3(95, 6), 256, 0, stream>>>(ADBF, WTIV, inj_bv, VINJ, NA_ADA, 768, 768);
  gemm_bf16_kernel<<<dim3(18, 2), 256, 0, stream>>>(QLN, WTIS, inj_bs, OFFI, LQ_VIT, 144, 768);
  gemm_bf16_kernel<<<dim3(18, 1), 256, 0, stream>>>(QLN, WTIA, inj_ba, AWLI, LQ_VIT, 72, 768);

  sampler_inj_kernel<<<3456, 256, 0, stream>>>(ref1, OFFI, AWLI, VINJ, SAMPI);

  gemm_bf16_kernel<<<dim3(18, 6), 256, 0, stream>>>(SAMPI, WTIO, inj_bo, ATTNI, LQ_VIT, 768, 768);
  residual_kernel<<<LQ_VIT, 768, 0, stream>>>(vit, ATTNI, inj_gamma, Q2, out_vit);

  ln_bf16_kernel<<<576, 256, 0, stream>>>(Q2, ext_vn_g, ext_vn_b, VLN, LQ_VIT);
  gemm_bf16_kernel<<<dim3(18, 6), 256, 0, stream>>>(VLN, WTEV, ext_bv, VEXT, LQ_VIT, 768, 768);
  gemm_bf16_kernel<<<dim3(95, 1), 256, 0, stream>>>(ADBF, WTES, ext_bs, OFFE, NA_ADA, 48, 768);
  gemm_bf16_kernel<<<dim3(95, 1), 256, 0, stream>>>(ADBF, WTEA, ext_ba, AWLE, NA_ADA, 24, 768);

  sampler_ext_kernel<<<18144, 256, 0, stream>>>(ref2, OFFE, AWLE, VEXT, SAMPE);

  gemm_bf16_kernel<<<dim3(95, 6), 256, 0, stream>>>(SAMPE, WTEO, ext_bo, ATTN2, NA_ADA, 768, 768);
  add_ln_f32_kernel<<<3024, 256, 0, stream>>>(adapter, ATTN2, ext_qn_g, ext_qn_b, out_ada, NA_ADA);
}

// Round 2
// 314.672 us; speedup vs baseline: 1.3813x; 1.3813x over previous
//
#include <hip/hip_runtime.h>

// InteractionBlock (ViT-Adapter injector+extractor with MSDeformAttn) for MI355X.
// R2: samplers restructured (2 heads/wave, float4 gathers, branchless masking),
// batched transposes, fused Ws+Wa GEMMs, fused residual+LN. 14 launches.

#define LQ_VIT 2304
#define NA_ADA 12096

typedef float f32x4 __attribute__((ext_vector_type(4)));
typedef short bf16x8 __attribute__((ext_vector_type(8)));

__device__ __forceinline__ unsigned short f2bf(float f) {
  unsigned u = __builtin_bit_cast(unsigned, f);
  u += 0x7FFFu + ((u >> 16) & 1u);   // round-to-nearest-even bf16
  return (unsigned short)(u >> 16);
}

__device__ __forceinline__ void gload_lds16(const void* g, void* l) {
  __builtin_amdgcn_global_load_lds(
      (__attribute__((address_space(1))) void*)(void*)g,
      (__attribute__((address_space(3))) void*)l, 16, 0, 0);
}

// ---------------- batched weight transpose + bf16 cast: W[768,N] -> WT[N,768] --
struct TransPack {
  const float* W[8];
  unsigned short* WT[8];
  int N[8];
};

__global__ __launch_bounds__(256) void transpose_batch_kernel(TransPack tp) {
  int z = blockIdx.z;
  const float* __restrict__ W = tp.W[z];
  unsigned short* __restrict__ WT = tp.WT[z];
  int N = tp.N[z];
  int kb = blockIdx.x * 32, nb = blockIdx.y * 32;
  if (nb >= N) return;  // block-uniform early exit (before any barrier)
  __shared__ float tile[32][33];
  int tx = threadIdx.x, ty = threadIdx.y;  // blockDim = (32, 8)
  for (int i = ty; i < 32; i += 8) {
    int k = kb + i, n = nb + tx;
    tile[i][tx] = (n < N) ? W[(size_t)k * N + n] : 0.f;  // K=768 always full
  }
  __syncthreads();
  for (int i = ty; i < 32; i += 8) {
    int n = nb + i, k = kb + tx;
    if (n < N) WT[(size_t)n * 768 + k] = f2bf(tile[tx][i]);
  }
}

// ---------------- bias concat (one tiny block) -------------------------------
__global__ void concat_bias_kernel(const float* __restrict__ isv, const float* __restrict__ iav,
                                   const float* __restrict__ esv, const float* __restrict__ eav,
                                   float* __restrict__ bi, float* __restrict__ be) {
  int i = threadIdx.x;
  if (i < 144) bi[i] = isv[i];
  else if (i < 216) bi[i] = iav[i - 144];
  if (i < 48) be[i] = esv[i];
  else if (i < 72) be[i] = eav[i - 48];
}

// ---------------- f32 -> bf16 cast (vectorized, n4 = count/4) ----------------
__global__ __launch_bounds__(256) void cast_bf16_kernel(
    const float* __restrict__ in, unsigned short* __restrict__ out, int n4) {
  int i = blockIdx.x * 256 + threadIdx.x;
  if (i < n4) {
    float4 v = ((const float4*)in)[i];
    ushort4 o;
    o.x = f2bf(v.x); o.y = f2bf(v.y); o.z = f2bf(v.z); o.w = f2bf(v.w);
    ((ushort4*)out)[i] = o;
  }
}

// ---------------- LayerNorm (row=768) -> bf16 out; one wave per row ----------
__global__ __launch_bounds__(256) void ln_bf16_kernel(
    const float* __restrict__ X, const float* __restrict__ g,
    const float* __restrict__ b, unsigned short* __restrict__ out, int R) {
  int wid = blockIdx.x * 4 + (threadIdx.x >> 6);
  int lane = threadIdx.x & 63;
  if (wid >= R) return;
  const float* row = X + (size_t)wid * 768;
  float x[12]; float s = 0.f;
#pragma unroll
  for (int j = 0; j < 12; j++) { x[j] = row[lane + j * 64]; s += x[j]; }
#pragma unroll
  for (int o = 32; o >= 1; o >>= 1) s += __shfl_xor(s, o);
  float mean = s * (1.f / 768.f);
  float v = 0.f;
#pragma unroll
  for (int j = 0; j < 12; j++) { float d = x[j] - mean; v += d * d; }
#pragma unroll
  for (int o = 32; o >= 1; o >>= 1) v += __shfl_xor(v, o);
  float rs = rsqrtf(v * (1.f / 768.f) + 1e-6f);
#pragma unroll
  for (int j = 0; j < 12; j++) {
    int c = lane + j * 64;
    out[(size_t)wid * 768 + c] = f2bf((x[j] - mean) * rs * g[c] + b[c]);
  }
}

// ---------------- fused residual + LayerNorm ---------------------------------
// val = vit + gamma*attn -> vout (f32, = vit_out); LN(val) -> vln (bf16)
__global__ __launch_bounds__(256) void residual_ln_kernel(
    const float* __restrict__ vit, const float* __restrict__ attn,
    const float* __restrict__ gamma, const float* __restrict__ g,
    const float* __restrict__ b, float* __restrict__ vout,
    unsigned short* __restrict__ vln, int R) {
  int wid = blockIdx.x * 4 + (threadIdx.x >> 6);
  int lane = threadIdx.x & 63;
  if (wid >= R) return;
  const float* ra = vit + (size_t)wid * 768;
  const float* rb = attn + (size_t)wid * 768;
  float x[12]; float s = 0.f;
#pragma unroll
  for (int j = 0; j < 12; j++) {
    int c = lane + j * 64;
    x[j] = ra[c] + gamma[c] * rb[c];
    vout[(size_t)wid * 768 + c] = x[j];
    s += x[j];
  }
#pragma unroll
  for (int o = 32; o >= 1; o >>= 1) s += __shfl_xor(s, o);
  float mean = s * (1.f / 768.f);
  float v = 0.f;
#pragma unroll
  for (int j = 0; j < 12; j++) { float d = x[j] - mean; v += d * d; }
#pragma unroll
  for (int o = 32; o >= 1; o >>= 1) v += __shfl_xor(v, o);
  float rs = rsqrtf(v * (1.f / 768.f) + 1e-6f);
#pragma unroll
  for (int j = 0; j < 12; j++) {
    int c = lane + j * 64;
    vln[(size_t)wid * 768 + c] = f2bf((x[j] - mean) * rs * g[c] + b[c]);
  }
}

// ---------------- add + LayerNorm -> f32 out; one wave per row ---------------
__global__ __launch_bounds__(256) void add_ln_f32_kernel(
    const float* __restrict__ Xa, const float* __restrict__ Xb,
    const float* __restrict__ g, const float* __restrict__ b,
    float* __restrict__ out, int R) {
  int wid = blockIdx.x * 4 + (threadIdx.x >> 6);
  int lane = threadIdx.x & 63;
  if (wid >= R) return;
  const float* ra = Xa + (size_t)wid * 768;
  const float* rb = Xb + (size_t)wid * 768;
  float x[12]; float s = 0.f;
#pragma unroll
  for (int j = 0; j < 12; j++) { x[j] = ra[lane + j * 64] + rb[lane + j * 64]; s += x[j]; }
#pragma unroll
  for (int o = 32; o >= 1; o >>= 1) s += __shfl_xor(s, o);
  float mean = s * (1.f / 768.f);
  float v = 0.f;
#pragma unroll
  for (int j = 0; j < 12; j++) { float d = x[j] - mean; v += d * d; }
#pragma unroll
  for (int o = 32; o >= 1; o >>= 1) v += __shfl_xor(v, o);
  float rs = rsqrtf(v * (1.f / 768.f) + 1e-6f);
#pragma unroll
  for (int j = 0; j < 12; j++) {
    int c = lane + j * 64;
    out[(size_t)wid * 768 + c] = (x[j] - mean) * rs * g[c] + b[c];
  }
}

// ---------------- bf16 MFMA GEMM: C[M,N] f32 = A[M,K]bf16 @ BT[N,K]bf16^T + bias
__global__ __launch_bounds__(256) void gemm_bf16_kernel(
    const unsigned short* __restrict__ A, const unsigned short* __restrict__ BT,
    const float* __restrict__ bias, float* __restrict__ C, int M, int N, int K) {
  const int BK = 64;
  __shared__ unsigned short As[128 * BK];
  __shared__ unsigned short Bs[128 * BK];
  int m0 = blockIdx.x * 128, n0 = blockIdx.y * 128;
  int tid = threadIdx.x;
  int w = tid >> 6, lane = tid & 63;
  int wr = w >> 1, wc = w & 1;
  int frow = lane & 15, fk = (lane >> 4) * 8;
  int sr = lane >> 3;
  int sk = (lane & 7) * 8;
  f32x4 acc[4][4] = {};
  int kTiles = K / BK;
  for (int kt = 0; kt < kTiles; kt++) {
    int k0 = kt * BK;
    __syncthreads();
#pragma unroll
    for (int i = 0; i < 4; i++) {
      int ch = w * 4 + i;
      int row = ch * 8 + sr;
      int gm = m0 + row; if (gm >= M) gm = M - 1;
      int gn = n0 + row; if (gn >= N) gn = N - 1;
      gload_lds16(&A[(size_t)gm * K + k0 + sk], &As[ch * 512]);
      gload_lds16(&BT[(size_t)gn * K + k0 + sk], &Bs[ch * 512]);
    }
    __syncthreads();
#pragma unroll
    for (int kk = 0; kk < BK; kk += 32) {
      bf16x8 af[4], bfr[4];
#pragma unroll
      for (int m = 0; m < 4; m++)
        af[m] = *(const bf16x8*)&As[(wr * 64 + m * 16 + frow) * BK + kk + fk];
#pragma unroll
      for (int n = 0; n < 4; n++)
        bfr[n] = *(const bf16x8*)&Bs[(wc * 64 + n * 16 + frow) * BK + kk + fk];
#pragma unroll
      for (int m = 0; m < 4; m++)
#pragma unroll
        for (int n = 0; n < 4; n++)
          acc[m][n] = __builtin_amdgcn_mfma_f32_16x16x32_bf16(af[m], bfr[n], acc[m][n], 0, 0, 0);
    }
  }
  int orow = (lane >> 4) * 4, ocol = lane & 15;
#pragma unroll
  for (int m = 0; m < 4; m++) {
    int gmb = m0 + wr * 64 + m * 16 + orow;
#pragma unroll
    for (int n = 0; n < 4; n++) {
      int gn = n0 + wc * 64 + n * 16 + ocol;
      if (gn < N) {
        float bv = bias[gn];
#pragma unroll
        for (int r = 0; r < 4; r++) {
          int gm = gmb + r;
          if (gm < M) C[(size_t)gm * N + gn] = acc[m][n][r] + bv;
        }
      }
    }
  }
}

// ---------------- deformable samplers ----------------------------------------
// One wave = (query, 2 heads). Lanes 0-31 head h0, lanes 32-63 head h1.
// Each lane covers 4 channels (float4). Branchless clamped gathers.

// Injector: Lq=2304, 6 heads, 3 levels {96,48,24}, 4 points.
// sa row (stride 216): off[((h*3+l)*4+p)*2 + xy] (0..143), logit[144 + h*12 + l*4+p]
__global__ __launch_bounds__(256) void sampler_inj_kernel(
    const float* __restrict__ ref, const float* __restrict__ sa,
    const float* __restrict__ v, unsigned short* __restrict__ out) {
  int gw = (blockIdx.x * 256 + threadIdx.x) >> 6;
  int lane = threadIdx.x & 63;
  int q = gw / 3, hp = gw - q * 3;
  if (q >= LQ_VIT) return;
  int h = hp * 2 + (lane >> 5);
  int c = h * 128 + (lane & 31) * 4;
  float rx = ref[q * 2], ry = ref[q * 2 + 1];
  const float* row = sa + (size_t)q * 216;
  float lg[12]; float mx = -1e30f;
#pragma unroll
  for (int i = 0; i < 12; i++) { lg[i] = row[144 + h * 12 + i]; mx = fmaxf(mx, lg[i]); }
  float s = 0.f;
#pragma unroll
  for (int i = 0; i < 12; i++) { lg[i] = __expf(lg[i] - mx); s += lg[i]; }
  float inv = 1.f / s;
  f32x4 acc = {0.f, 0.f, 0.f, 0.f};
  const int LW[3] = {96, 48, 24};
  const int LS[3] = {0, 9216, 11520};
#pragma unroll
  for (int l = 0; l < 3; l++) {
    const int Wl = LW[l], st = LS[l], Wm = Wl - 1;
    const float Wf = (float)Wl;
#pragma unroll
    for (int p = 0; p < 4; p++) {
      int ob = ((h * 3 + l) * 4 + p) * 2;
      float ix = fmaf(rx, Wf, row[ob]) - 0.5f;
      float iy = fmaf(ry, Wf, row[ob + 1]) - 0.5f;
      float x0f = floorf(ix), y0f = floorf(iy);
      float wx = ix - x0f, wy = iy - y0f;
      int x0 = (int)x0f, y0 = (int)y0f;
      float aw = lg[l * 4 + p] * inv;
      float wy0 = (1.f - wy) * aw, wy1 = wy * aw;
      float w00 = (1.f - wx) * wy0, w01 = wx * wy0;
      float w10 = (1.f - wx) * wy1, w11 = wx * wy1;
      bool xv0 = (unsigned)x0 < (unsigned)Wl, xv1 = (unsigned)(x0 + 1) < (unsigned)Wl;
      bool yv0 = (unsigned)y0 < (unsigned)Wl, yv1 = (unsigned)(y0 + 1) < (unsigned)Wl;
      w00 = (xv0 && yv0) ? w00 : 0.f;
      w01 = (xv1 && yv0) ? w01 : 0.f;
      w10 = (xv0 && yv1) ? w10 : 0.f;
      w11 = (xv1 && yv1) ? w11 : 0.f;
      int x0c = min(max(x0, 0), Wm), x1c = min(max(x0 + 1, 0), Wm);
      int y0c = min(max(y0, 0), Wm), y1c = min(max(y0 + 1, 0), Wm);
      const float* r0 = v + ((size_t)(st + y0c * Wl) * 768 + c);
      const float* r1 = v + ((size_t)(st + y1c * Wl) * 768 + c);
      f32x4 v00 = *(const f32x4*)(r0 + (size_t)x0c * 768);
      f32x4 v01 = *(const f32x4*)(r0 + (size_t)x1c * 768);
      f32x4 v10 = *(const f32x4*)(r1 + (size_t)x0c * 768);
      f32x4 v11 = *(const f32x4*)(r1 + (size_t)x1c * 768);
      acc += w00 * v00 + w01 * v01 + w10 * v10 + w11 * v11;
    }
  }
  ushort4 o4;
  o4.x = f2bf(acc[0]); o4.y = f2bf(acc[1]); o4.z = f2bf(acc[2]); o4.w = f2bf(acc[3]);
  *(ushort4*)&out[(size_t)q * 768 + c] = o4;
}

// Extractor: Lq=12096, 6 heads, 1 level (48x48), 4 points.
// sa row (stride 72): off[(h*4+p)*2 + xy] (0..47), logit[48 + h*4 + p]
__global__ __launch_bounds__(256) void sampler_ext_kernel(
    const float* __restrict__ ref, const float* __restrict__ sa,
    const float* __restrict__ v, unsigned short* __restrict__ out) {
  int gw = (blockIdx.x * 256 + threadIdx.x) >> 6;
  int lane = threadIdx.x & 63;
  int q = gw / 3, hp = gw - q * 3;
  if (q >= NA_ADA) return;
  int h = hp * 2 + (lane >> 5);
  int c = h * 128 + (lane & 31) * 4;
  float rx = ref[q * 2], ry = ref[q * 2 + 1];
  const float* row = sa + (size_t)q * 72;
  float lg[4]; float mx = -1e30f;
#pragma unroll
  for (int p = 0; p < 4; p++) { lg[p] = row[48 + h * 4 + p]; mx = fmaxf(mx, lg[p]); }
  float s = 0.f;
#pragma unroll
  for (int p = 0; p < 4; p++) { lg[p] = __expf(lg[p] - mx); s += lg[p]; }
  float inv = 1.f / s;
  f32x4 acc = {0.f, 0.f, 0.f, 0.f};
#pragma unroll
  for (int p = 0; p < 4; p++) {
    int ob = (h * 4 + p) * 2;
    float ix = fmaf(rx, 48.f, row[ob]) - 0.5f;
    float iy = fmaf(ry, 48.f, row[ob + 1]) - 0.5f;
    float x0f = floorf(ix), y0f = floorf(iy);
    float wx = ix - x0f, wy = iy - y0f;
    int x0 = (int)x0f, y0 = (int)y0f;
    float aw = lg[p] * inv;
    float wy0 = (1.f - wy) * aw, wy1 = wy * aw;
    float w00 = (1.f - wx) * wy0, w01 = wx * wy0;
    float w10 = (1.f - wx) * wy1, w11 = wx * wy1;
    bool xv0 = (unsigned)x0 < 48u, xv1 = (unsigned)(x0 + 1) < 48u;
    bool yv0 = (unsigned)y0 < 48u, yv1 = (unsigned)(y0 + 1) < 48u;
    w00 = (xv0 && yv0) ? w00 : 0.f;
    w01 = (xv1 && yv0) ? w01 : 0.f;
    w10 = (xv0 && yv1) ? w10 : 0.f;
    w11 = (xv1 && yv1) ? w11 : 0.f;
    int x0c = min(max(x0, 0), 47), x1c = min(max(x0 + 1, 0), 47);
    int y0c = min(max(y0, 0), 47), y1c = min(max(y0 + 1, 0), 47);
    const float* r0 = v + ((size_t)(y0c * 48) * 768 + c);
    const float* r1 = v + ((size_t)(y1c * 48) * 768 + c);
    f32x4 v00 = *(const f32x4*)(r0 + (size_t)x0c * 768);
    f32x4 v01 = *(const f32x4*)(r0 + (size_t)x1c * 768);
    f32x4 v10 = *(const f32x4*)(r1 + (size_t)x0c * 768);
    f32x4 v11 = *(const f32x4*)(r1 + (size_t)x1c * 768);
    acc += w00 * v00 + w01 * v01 + w10 * v10 + w11 * v11;
  }
  ushort4 o4;
  o4.x = f2bf(acc[0]); o4.y = f2bf(acc[1]); o4.z = f2bf(acc[2]); o4.w = f2bf(acc[3]);
  *(ushort4*)&out[(size_t)q * 768 + c] = o4;
}

extern "C" void kernel_launch(void* const* d_in, const int* in_sizes, int n_in,
                              void* d_out, int out_size, void* d_ws, size_t ws_size,
                              hipStream_t stream) {
  (void)in_sizes; (void)n_in; (void)out_size; (void)ws_size;
  const float* vit      = (const float*)d_in[0];
  const float* adapter  = (const float*)d_in[1];
  const float* ref1     = (const float*)d_in[2];
  const float* ref2     = (const float*)d_in[3];
  const float* inj_qn_g = (const float*)d_in[4];
  const float* inj_qn_b = (const float*)d_in[5];
  const float* inj_Wv   = (const float*)d_in[6];
  const float* inj_bv   = (const float*)d_in[7];
  const float* inj_Ws   = (const float*)d_in[8];
  const float* inj_bs   = (const float*)d_in[9];
  const float* inj_Wa   = (const float*)d_in[10];
  const float* inj_ba   = (const float*)d_in[11];
  const float* inj_Wo   = (const float*)d_in[12];
  const float* inj_bo   = (const float*)d_in[13];
  const float* inj_gamma= (const float*)d_in[14];
  const float* ext_vn_g = (const float*)d_in[15];
  const float* ext_vn_b = (const float*)d_in[16];
  const float* ext_qn_g = (const float*)d_in[17];
  const float* ext_qn_b = (const float*)d_in[18];
  const float* ext_Wv   = (const float*)d_in[19];
  const float* ext_bv   = (const float*)d_in[20];
  const float* ext_Ws   = (const float*)d_in[21];
  const float* ext_bs   = (const float*)d_in[22];
  const float* ext_Wa   = (const float*)d_in[23];
  const float* ext_ba   = (const float*)d_in[24];
  const float* ext_Wo   = (const float*)d_in[25];
  const float* ext_bo   = (const float*)d_in[26];

  size_t cur = 0;
  auto take = [&](size_t bytes) {
    void* p = (char*)d_ws + cur;
    cur += (bytes + 255) & ~(size_t)255;
    return p;
  };
  unsigned short* WTIV = (unsigned short*)take((size_t)768 * 768 * 2);
  unsigned short* WTIO = (unsigned short*)take((size_t)768 * 768 * 2);
  unsigned short* WTEV = (unsigned short*)take((size_t)768 * 768 * 2);
  unsigned short* WTEO = (unsigned short*)take((size_t)768 * 768 * 2);
  unsigned short* WSAI = (unsigned short*)take((size_t)216 * 768 * 2);
  unsigned short* WSAE = (unsigned short*)take((size_t)72 * 768 * 2);
  float* BCI = (float*)take((size_t)216 * 4);
  float* BCE = (float*)take((size_t)72 * 4);
  unsigned short* ADBF = (unsigned short*)take((size_t)NA_ADA * 768 * 2);
  unsigned short* QLN  = (unsigned short*)take((size_t)LQ_VIT * 768 * 2);
  float* VINJ  = (float*)take((size_t)NA_ADA * 768 * 4);
  float* SAI   = (float*)take((size_t)LQ_VIT * 216 * 4);
  unsigned short* SAMPI = (unsigned short*)take((size_t)LQ_VIT * 768 * 2);
  float* ATTNI = (float*)take((size_t)LQ_VIT * 768 * 4);
  unsigned short* VLN  = (unsigned short*)take((size_t)LQ_VIT * 768 * 2);
  float* VEXT  = (float*)take((size_t)LQ_VIT * 768 * 4);
  float* SAE   = (float*)take((size_t)NA_ADA * 72 * 4);
  unsigned short* SAMPE = ADBF;  // adapter_bf16 dead after ext S+A GEMM
  float* ATTN2 = VINJ;           // v_inj dead after injector sampling

  float* out_vit = (float*)d_out;
  float* out_ada = out_vit + (size_t)LQ_VIT * 768;

  TransPack tp;
  tp.W[0] = inj_Wv; tp.WT[0] = WTIV; tp.N[0] = 768;
  tp.W[1] = inj_Wo; tp.WT[1] = WTIO; tp.N[1] = 768;
  tp.W[2] = ext_Wv; tp.WT[2] = WTEV; tp.N[2] = 768;
  tp.W[3] = ext_Wo; tp.WT[3] = WTEO; tp.N[3] = 768;
  tp.W[4] = inj_Ws; tp.WT[4] = WSAI;               tp.N[4] = 144;
  tp.W[5] = inj_Wa; tp.WT[5] = WSAI + 144 * 768;   tp.N[5] = 72;
  tp.W[6] = ext_Ws; tp.WT[6] = WSAE;               tp.N[6] = 48;
  tp.W[7] = ext_Wa; tp.WT[7] = WSAE + 48 * 768;    tp.N[7] = 24;
  transpose_batch_kernel<<<dim3(24, 24, 8), dim3(32, 8), 0, stream>>>(tp);
  concat_bias_kernel<<<1, 256, 0, stream>>>(inj_bs, inj_ba, ext_bs, ext_ba, BCI, BCE);

  cast_bf16_kernel<<<9072, 256, 0, stream>>>(adapter, ADBF, (NA_ADA * 768) / 4);
  ln_bf16_kernel<<<576, 256, 0, stream>>>(vit, inj_qn_g, inj_qn_b, QLN, LQ_VIT);

  gemm_bf16_kernel<<<dim3(95, 6), 256, 0, stream>>>(ADBF, WTIV, inj_bv, VINJ, NA_ADA, 768, 768);
  gemm_bf16_kernel<<<dim3(18, 2), 256, 0, stream>>>(QLN, WSAI, BCI, SAI, LQ_VIT, 216, 768);

  sampler_inj_kernel<<<1728, 256, 0, stream>>>(ref1, SAI, VINJ, SAMPI);

  gemm_bf16_kernel<<<dim3(18, 6), 256, 0, stream>>>(SAMPI, WTIO, inj_bo, ATTNI, LQ_VIT, 768, 768);
  residual_ln_kernel<<<576, 256, 0, stream>>>(vit, ATTNI, inj_gamma, ext_vn_g, ext_vn_b,
                                              out_vit, VLN, LQ_VIT);

  gemm_bf16_kernel<<<dim3(18, 6), 256, 0, stream>>>(VLN, WTEV, ext_bv, VEXT, LQ_VIT, 768, 768);
  gemm_bf16_kernel<<<dim3(95, 1), 256, 0, stream>>>(ADBF, WSAE, BCE, SAE, NA_ADA, 72, 768);

  sampler_ext_kernel<<<9072, 256, 0, stream>>>(ref2, SAE, VEXT, SAMPE);

  gemm_bf16_kernel<<<dim3(95, 6), 256, 0, stream>>>(SAMPE, WTEO, ext_bo, ATTN2, NA_ADA, 768, 768);
  add_ln_f32_kernel<<<3024, 256, 0, stream>>>(adapter, ATTN2, ext_qn_g, ext_qn_b, out_ada, NA_ADA);
}

// Round 3
// 254.088 us; speedup vs baseline: 1.7107x; 1.2384x over previous
//
#include <hip/hip_runtime.h>

// InteractionBlock (ViT-Adapter injector+extractor with MSDeformAttn) for MI355X.
// R3: 2-phase double-buffered GEMM (stage-ahead, 1 barrier/K-step), fused
// inj_Wv+ext_S/A GEMM (N=840), BM=64 tiles for M=2304 GEMMs, XCD swizzle.

#define LQ_VIT 2304
#define NA_ADA 12096

typedef float f32x4 __attribute__((ext_vector_type(4)));
typedef short bf16x8 __attribute__((ext_vector_type(8)));

__device__ __forceinline__ unsigned short f2bf(float f) {
  unsigned u = __builtin_bit_cast(unsigned, f);
  u += 0x7FFFu + ((u >> 16) & 1u);   // round-to-nearest-even bf16
  return (unsigned short)(u >> 16);
}

__device__ __forceinline__ void gload_lds16(const void* g, void* l) {
  __builtin_amdgcn_global_load_lds(
      (__attribute__((address_space(1))) void*)(void*)g,
      (__attribute__((address_space(3))) void*)l, 16, 0, 0);
}

// ---------------- batched weight transpose + bf16 cast: W[768,N] -> WT[N,768] --
struct TransPack {
  const float* W[8];
  unsigned short* WT[8];
  int N[8];
};

__global__ __launch_bounds__(256) void transpose_batch_kernel(TransPack tp) {
  int z = blockIdx.z;
  const float* __restrict__ W = tp.W[z];
  unsigned short* __restrict__ WT = tp.WT[z];
  int N = tp.N[z];
  int kb = blockIdx.x * 32, nb = blockIdx.y * 32;
  if (nb >= N) return;  // block-uniform early exit (before any barrier)
  __shared__ float tile[32][33];
  int tx = threadIdx.x, ty = threadIdx.y;  // blockDim = (32, 8)
  for (int i = ty; i < 32; i += 8) {
    int k = kb + i, n = nb + tx;
    tile[i][tx] = (n < N) ? W[(size_t)k * N + n] : 0.f;  // K=768 always full
  }
  __syncthreads();
  for (int i = ty; i < 32; i += 8) {
    int n = nb + i, k = kb + tx;
    if (n < N) WT[(size_t)n * 768 + k] = f2bf(tile[tx][i]);
  }
}

// ---------------- bias concats -----------------------------------------------
__global__ void concat_bias_kernel(const float* __restrict__ isv, const float* __restrict__ iav,
                                   const float* __restrict__ ibv, const float* __restrict__ esv,
                                   const float* __restrict__ eav,
                                   float* __restrict__ bci, float* __restrict__ bbig) {
  int i = threadIdx.x;  // 1024 threads
  if (i < 144) bci[i] = isv[i];
  else if (i < 216) bci[i] = iav[i - 144];
  if (i < 768) bbig[i] = ibv[i];
  else if (i < 816) bbig[i] = esv[i - 768];
  else if (i < 840) bbig[i] = eav[i - 816];
}

// ---------------- f32 -> bf16 cast (vectorized, n4 = count/4) ----------------
__global__ __launch_bounds__(256) void cast_bf16_kernel(
    const float* __restrict__ in, unsigned short* __restrict__ out, int n4) {
  int i = blockIdx.x * 256 + threadIdx.x;
  if (i < n4) {
    float4 v = ((const float4*)in)[i];
    ushort4 o;
    o.x = f2bf(v.x); o.y = f2bf(v.y); o.z = f2bf(v.z); o.w = f2bf(v.w);
    ((ushort4*)out)[i] = o;
  }
}

// ---------------- LayerNorm (row=768) -> bf16 out; one wave per row ----------
__global__ __launch_bounds__(256) void ln_bf16_kernel(
    const float* __restrict__ X, const float* __restrict__ g,
    const float* __restrict__ b, unsigned short* __restrict__ out, int R) {
  int wid = blockIdx.x * 4 + (threadIdx.x >> 6);
  int lane = threadIdx.x & 63;
  if (wid >= R) return;
  const float* row = X + (size_t)wid * 768;
  float x[12]; float s = 0.f;
#pragma unroll
  for (int j = 0; j < 12; j++) { x[j] = row[lane + j * 64]; s += x[j]; }
#pragma unroll
  for (int o = 32; o >= 1; o >>= 1) s += __shfl_xor(s, o);
  float mean = s * (1.f / 768.f);
  float v = 0.f;
#pragma unroll
  for (int j = 0; j < 12; j++) { float d = x[j] - mean; v += d * d; }
#pragma unroll
  for (int o = 32; o >= 1; o >>= 1) v += __shfl_xor(v, o);
  float rs = rsqrtf(v * (1.f / 768.f) + 1e-6f);
#pragma unroll
  for (int j = 0; j < 12; j++) {
    int c = lane + j * 64;
    out[(size_t)wid * 768 + c] = f2bf((x[j] - mean) * rs * g[c] + b[c]);
  }
}

// ---------------- fused residual + LayerNorm ---------------------------------
__global__ __launch_bounds__(256) void residual_ln_kernel(
    const float* __restrict__ vit, const float* __restrict__ attn,
    const float* __restrict__ gamma, const float* __restrict__ g,
    const float* __restrict__ b, float* __restrict__ vout,
    unsigned short* __restrict__ vln, int R) {
  int wid = blockIdx.x * 4 + (threadIdx.x >> 6);
  int lane = threadIdx.x & 63;
  if (wid >= R) return;
  const float* ra = vit + (size_t)wid * 768;
  const float* rb = attn + (size_t)wid * 768;
  float x[12]; float s = 0.f;
#pragma unroll
  for (int j = 0; j < 12; j++) {
    int c = lane + j * 64;
    x[j] = ra[c] + gamma[c] * rb[c];
    vout[(size_t)wid * 768 + c] = x[j];
    s += x[j];
  }
#pragma unroll
  for (int o = 32; o >= 1; o >>= 1) s += __shfl_xor(s, o);
  float mean = s * (1.f / 768.f);
  float v = 0.f;
#pragma unroll
  for (int j = 0; j < 12; j++) { float d = x[j] - mean; v += d * d; }
#pragma unroll
  for (int o = 32; o >= 1; o >>= 1) v += __shfl_xor(v, o);
  float rs = rsqrtf(v * (1.f / 768.f) + 1e-6f);
#pragma unroll
  for (int j = 0; j < 12; j++) {
    int c = lane + j * 64;
    vln[(size_t)wid * 768 + c] = f2bf((x[j] - mean) * rs * g[c] + b[c]);
  }
}

// ---------------- add + LayerNorm -> f32 out; one wave per row ---------------
__global__ __launch_bounds__(256) void add_ln_f32_kernel(
    const float* __restrict__ Xa, const float* __restrict__ Xb,
    const float* __restrict__ g, const float* __restrict__ b,
    float* __restrict__ out, int R) {
  int wid = blockIdx.x * 4 + (threadIdx.x >> 6);
  int lane = threadIdx.x & 63;
  if (wid >= R) return;
  const float* ra = Xa + (size_t)wid * 768;
  const float* rb = Xb + (size_t)wid * 768;
  float x[12]; float s = 0.f;
#pragma unroll
  for (int j = 0; j < 12; j++) { x[j] = ra[lane + j * 64] + rb[lane + j * 64]; s += x[j]; }
#pragma unroll
  for (int o = 32; o >= 1; o >>= 1) s += __shfl_xor(s, o);
  float mean = s * (1.f / 768.f);
  float v = 0.f;
#pragma unroll
  for (int j = 0; j < 12; j++) { float d = x[j] - mean; v += d * d; }
#pragma unroll
  for (int o = 32; o >= 1; o >>= 1) v += __shfl_xor(v, o);
  float rs = rsqrtf(v * (1.f / 768.f) + 1e-6f);
#pragma unroll
  for (int j = 0; j < 12; j++) {
    int c = lane + j * 64;
    out[(size_t)wid * 768 + c] = (x[j] - mean) * rs * g[c] + b[c];
  }
}

// ---------------- 2-phase double-buffered bf16 MFMA GEMM ---------------------
// C[M,N] f32 = A[M,K]bf16 @ BT[N,K]^T + bias. BN=128; BM in {64,128}.
// Stage tile t+1 before computing tile t; single barrier per K-step.
template<int BM>
__global__ __launch_bounds__(256) void gemm2_kernel(
    const unsigned short* __restrict__ A, const unsigned short* __restrict__ BT,
    const float* __restrict__ bias, float* __restrict__ C,
    int M, int N, int K, int MT) {
  constexpr int BN = 128;
  constexpr int WAVES_M = BM / 64;                 // 2 or 1
  constexpr int WN = (WAVES_M == 2) ? 64 : 32;     // per-wave N
  constexpr int FM = 4, FN = WN / 16;              // frag counts
  constexpr int CH_A = BM / 8, CH = CH_A + BN / 8; // 1KB staging chunks
  constexpr int TILE = (BM + BN) * 64;             // shorts per buffer
  __shared__ unsigned short lds[2 * TILE];

  // bijective XCD-aware swizzle (m204): each XCD gets a contiguous wg chunk
  int nwg = gridDim.x;
  int id = blockIdx.x;
  int qq = nwg >> 3, rr = nwg & 7;
  int xcd = id & 7, idx = id >> 3;
  int wg = (xcd < rr ? xcd * (qq + 1) : rr * (qq + 1) + (xcd - rr) * qq) + idx;
  int mt = wg % MT, nt = wg / MT;
  int m0 = mt * BM, n0 = nt * BN;

  int tid = threadIdx.x;
  int w = tid >> 6, lane = tid & 63;
  int wr = (WAVES_M == 2) ? (w >> 1) : 0;
  int wc = (WAVES_M == 2) ? (w & 1) : w;
  int frow = lane & 15, fk = (lane >> 4) * 8;
  int sr = lane >> 3, sk = (lane & 7) * 8;

  f32x4 acc[FM][FN] = {};
  int kT = K >> 6;

  auto stage = [&](int buf, int k0) {
    unsigned short* dst = lds + buf * TILE;
#pragma unroll
    for (int i = 0; i < CH / 4; i++) {
      int c = w + i * 4;
      if (c < CH_A) {
        int gm = m0 + c * 8 + sr; if (gm >= M) gm = M - 1;
        gload_lds16(&A[(size_t)gm * K + k0 + sk], &dst[c * 512]);
      } else {
        int gn = n0 + (c - CH_A) * 8 + sr; if (gn >= N) gn = N - 1;
        gload_lds16(&BT[(size_t)gn * K + k0 + sk], &dst[c * 512]);
      }
    }
  };

  stage(0, 0);
  __syncthreads();  // implicit vmcnt(0) drain: tile 0 ready
  for (int kt = 0; kt < kT; kt++) {
    int buf = kt & 1;
    if (kt + 1 < kT) stage(buf ^ 1, (kt + 1) << 6);  // in flight under compute
    const unsigned short* As_ = lds + buf * TILE;
    const unsigned short* Bs_ = As_ + BM * 64;
#pragma unroll
    for (int kk = 0; kk < 64; kk += 32) {
      bf16x8 af[FM], bfr[FN];
#pragma unroll
      for (int m = 0; m < FM; m++)
        af[m] = *(const bf16x8*)&As_[(wr * 64 + m * 16 + frow) * 64 + kk + fk];
#pragma unroll
      for (int n = 0; n < FN; n++)
        bfr[n] = *(const bf16x8*)&Bs_[(wc * WN + n * 16 + frow) * 64 + kk + fk];
#pragma unroll
      for (int m = 0; m < FM; m++)
#pragma unroll
        for (int n = 0; n < FN; n++)
          acc[m][n] = __builtin_amdgcn_mfma_f32_16x16x32_bf16(af[m], bfr[n], acc[m][n], 0, 0, 0);
    }
    __syncthreads();  // drains next-tile loads + protects LDS reuse
  }

  int orow = (lane >> 4) * 4, ocol = lane & 15;
#pragma unroll
  for (int m = 0; m < FM; m++) {
    int gmb = m0 + wr * 64 + m * 16 + orow;
#pragma unroll
    for (int n = 0; n < FN; n++) {
      int gn = n0 + wc * WN + n * 16 + ocol;
      if (gn < N) {
        float bv = bias[gn];
#pragma unroll
        for (int r = 0; r < 4; r++) {
          int gm = gmb + r;
          if (gm < M) C[(size_t)gm * N + gn] = acc[m][n][r] + bv;
        }
      }
    }
  }
}

// ---------------- deformable samplers ----------------------------------------
// One wave = (query, 2 heads). Lanes 0-31 head h0, lanes 32-63 head h1.
// Each lane covers 4 channels (float4). Branchless clamped gathers.

// Injector: Lq=2304, 6 heads, 3 levels {96,48,24}, 4 points. v row stride vst.
__global__ __launch_bounds__(256) void sampler_inj_kernel(
    const float* __restrict__ ref, const float* __restrict__ sa,
    const float* __restrict__ v, unsigned short* __restrict__ out, int vst) {
  int gw = (blockIdx.x * 256 + threadIdx.x) >> 6;
  int lane = threadIdx.x & 63;
  int q = gw / 3, hp = gw - q * 3;
  if (q >= LQ_VIT) return;
  int h = hp * 2 + (lane >> 5);
  int c = h * 128 + (lane & 31) * 4;
  float rx = ref[q * 2], ry = ref[q * 2 + 1];
  const float* row = sa + (size_t)q * 216;
  float lg[12]; float mx = -1e30f;
#pragma unroll
  for (int i = 0; i < 12; i++) { lg[i] = row[144 + h * 12 + i]; mx = fmaxf(mx, lg[i]); }
  float s = 0.f;
#pragma unroll
  for (int i = 0; i < 12; i++) { lg[i] = __expf(lg[i] - mx); s += lg[i]; }
  float inv = 1.f / s;
  f32x4 acc = {0.f, 0.f, 0.f, 0.f};
  const int LW[3] = {96, 48, 24};
  const int LS[3] = {0, 9216, 11520};
#pragma unroll
  for (int l = 0; l < 3; l++) {
    const int Wl = LW[l], st = LS[l], Wm = Wl - 1;
    const float Wf = (float)Wl;
#pragma unroll
    for (int p = 0; p < 4; p++) {
      int ob = ((h * 3 + l) * 4 + p) * 2;
      float ix = fmaf(rx, Wf, row[ob]) - 0.5f;
      float iy = fmaf(ry, Wf, row[ob + 1]) - 0.5f;
      float x0f = floorf(ix), y0f = floorf(iy);
      float wx = ix - x0f, wy = iy - y0f;
      int x0 = (int)x0f, y0 = (int)y0f;
      float aw = lg[l * 4 + p] * inv;
      float wy0 = (1.f - wy) * aw, wy1 = wy * aw;
      float w00 = (1.f - wx) * wy0, w01 = wx * wy0;
      float w10 = (1.f - wx) * wy1, w11 = wx * wy1;
      bool xv0 = (unsigned)x0 < (unsigned)Wl, xv1 = (unsigned)(x0 + 1) < (unsigned)Wl;
      bool yv0 = (unsigned)y0 < (unsigned)Wl, yv1 = (unsigned)(y0 + 1) < (unsigned)Wl;
      w00 = (xv0 && yv0) ? w00 : 0.f;
      w01 = (xv1 && yv0) ? w01 : 0.f;
      w10 = (xv0 && yv1) ? w10 : 0.f;
      w11 = (xv1 && yv1) ? w11 : 0.f;
      int x0c = min(max(x0, 0), Wm), x1c = min(max(x0 + 1, 0), Wm);
      int y0c = min(max(y0, 0), Wm), y1c = min(max(y0 + 1, 0), Wm);
      const float* r0 = v + ((size_t)(st + y0c * Wl) * vst + c);
      const float* r1 = v + ((size_t)(st + y1c * Wl) * vst + c);
      f32x4 v00 = *(const f32x4*)(r0 + (size_t)x0c * vst);
      f32x4 v01 = *(const f32x4*)(r0 + (size_t)x1c * vst);
      f32x4 v10 = *(const f32x4*)(r1 + (size_t)x0c * vst);
      f32x4 v11 = *(const f32x4*)(r1 + (size_t)x1c * vst);
      acc += w00 * v00 + w01 * v01 + w10 * v10 + w11 * v11;
    }
  }
  ushort4 o4;
  o4.x = f2bf(acc[0]); o4.y = f2bf(acc[1]); o4.z = f2bf(acc[2]); o4.w = f2bf(acc[3]);
  *(ushort4*)&out[(size_t)q * 768 + c] = o4;
}

// Extractor: Lq=12096, 6 heads, 1 level (48x48), 4 points. sa row stride sst.
__global__ __launch_bounds__(256) void sampler_ext_kernel(
    const float* __restrict__ ref, const float* __restrict__ sa, int sst,
    const float* __restrict__ v, unsigned short* __restrict__ out) {
  int gw = (blockIdx.x * 256 + threadIdx.x) >> 6;
  int lane = threadIdx.x & 63;
  int q = gw / 3, hp = gw - q * 3;
  if (q >= NA_ADA) return;
  int h = hp * 2 + (lane >> 5);
  int c = h * 128 + (lane & 31) * 4;
  float rx = ref[q * 2], ry = ref[q * 2 + 1];
  const float* row = sa + (size_t)q * sst;
  float lg[4]; float mx = -1e30f;
#pragma unroll
  for (int p = 0; p < 4; p++) { lg[p] = row[48 + h * 4 + p]; mx = fmaxf(mx, lg[p]); }
  float s = 0.f;
#pragma unroll
  for (int p = 0; p < 4; p++) { lg[p] = __expf(lg[p] - mx); s += lg[p]; }
  float inv = 1.f / s;
  f32x4 acc = {0.f, 0.f, 0.f, 0.f};
#pragma unroll
  for (int p = 0; p < 4; p++) {
    int ob = (h * 4 + p) * 2;
    float ix = fmaf(rx, 48.f, row[ob]) - 0.5f;
    float iy = fmaf(ry, 48.f, row[ob + 1]) - 0.5f;
    float x0f = floorf(ix), y0f = floorf(iy);
    float wx = ix - x0f, wy = iy - y0f;
    int x0 = (int)x0f, y0 = (int)y0f;
    float aw = lg[p] * inv;
    float wy0 = (1.f - wy) * aw, wy1 = wy * aw;
    float w00 = (1.f - wx) * wy0, w01 = wx * wy0;
    float w10 = (1.f - wx) * wy1, w11 = wx * wy1;
    bool xv0 = (unsigned)x0 < 48u, xv1 = (unsigned)(x0 + 1) < 48u;
    bool yv0 = (unsigned)y0 < 48u, yv1 = (unsigned)(y0 + 1) < 48u;
    w00 = (xv0 && yv0) ? w00 : 0.f;
    w01 = (xv1 && yv0) ? w01 : 0.f;
    w10 = (xv0 && yv1) ? w10 : 0.f;
    w11 = (xv1 && yv1) ? w11 : 0.f;
    int x0c = min(max(x0, 0), 47), x1c = min(max(x0 + 1, 0), 47);
    int y0c = min(max(y0, 0), 47), y1c = min(max(y0 + 1, 0), 47);
    const float* r0 = v + ((size_t)(y0c * 48) * 768 + c);
    const float* r1 = v + ((size_t)(y1c * 48) * 768 + c);
    f32x4 v00 = *(const f32x4*)(r0 + (size_t)x0c * 768);
    f32x4 v01 = *(const f32x4*)(r0 + (size_t)x1c * 768);
    f32x4 v10 = *(const f32x4*)(r1 + (size_t)x0c * 768);
    f32x4 v11 = *(const f32x4*)(r1 + (size_t)x1c * 768);
    acc += w00 * v00 + w01 * v01 + w10 * v10 + w11 * v11;
  }
  ushort4 o4;
  o4.x = f2bf(acc[0]); o4.y = f2bf(acc[1]); o4.z = f2bf(acc[2]); o4.w = f2bf(acc[3]);
  *(ushort4*)&out[(size_t)q * 768 + c] = o4;
}

extern "C" void kernel_launch(void* const* d_in, const int* in_sizes, int n_in,
                              void* d_out, int out_size, void* d_ws, size_t ws_size,
                              hipStream_t stream) {
  (void)in_sizes; (void)n_in; (void)out_size; (void)ws_size;
  const float* vit      = (const float*)d_in[0];
  const float* adapter  = (const float*)d_in[1];
  const float* ref1     = (const float*)d_in[2];
  const float* ref2     = (const float*)d_in[3];
  const float* inj_qn_g = (const float*)d_in[4];
  const float* inj_qn_b = (const float*)d_in[5];
  const float* inj_Wv   = (const float*)d_in[6];
  const float* inj_bv   = (const float*)d_in[7];
  const float* inj_Ws   = (const float*)d_in[8];
  const float* inj_bs   = (const float*)d_in[9];
  const float* inj_Wa   = (const float*)d_in[10];
  const float* inj_ba   = (const float*)d_in[11];
  const float* inj_Wo   = (const float*)d_in[12];
  const float* inj_bo   = (const float*)d_in[13];
  const float* inj_gamma= (const float*)d_in[14];
  const float* ext_vn_g = (const float*)d_in[15];
  const float* ext_vn_b = (const float*)d_in[16];
  const float* ext_qn_g = (const float*)d_in[17];
  const float* ext_qn_b = (const float*)d_in[18];
  const float* ext_Wv   = (const float*)d_in[19];
  const float* ext_bv   = (const float*)d_in[20];
  const float* ext_Ws   = (const float*)d_in[21];
  const float* ext_bs   = (const float*)d_in[22];
  const float* ext_Wa   = (const float*)d_in[23];
  const float* ext_ba   = (const float*)d_in[24];
  const float* ext_Wo   = (const float*)d_in[25];
  const float* ext_bo   = (const float*)d_in[26];

  size_t cur = 0;
  auto take = [&](size_t bytes) {
    void* p = (char*)d_ws + cur;
    cur += (bytes + 255) & ~(size_t)255;
    return p;
  };
  unsigned short* WBIG = (unsigned short*)take((size_t)840 * 768 * 2);  // [inj_Wv;ext_Ws;ext_Wa]^T
  unsigned short* WTIO = (unsigned short*)take((size_t)768 * 768 * 2);
  unsigned short* WTEV = (unsigned short*)take((size_t)768 * 768 * 2);
  unsigned short* WTEO = (unsigned short*)take((size_t)768 * 768 * 2);
  unsigned short* WSAI = (unsigned short*)take((size_t)216 * 768 * 2);
  float* BCI  = (float*)take((size_t)216 * 4);
  float* BBIG = (float*)take((size_t)840 * 4);
  unsigned short* ADBF = (unsigned short*)take((size_t)NA_ADA * 768 * 2);
  unsigned short* QLN  = (unsigned short*)take((size_t)LQ_VIT * 768 * 2);
  float* CBIG  = (float*)take((size_t)NA_ADA * 840 * 4);  // [v_inj | sae] stride 840
  float* SAI   = (float*)take((size_t)LQ_VIT * 216 * 4);
  unsigned short* SAMPI = (unsigned short*)take((size_t)LQ_VIT * 768 * 2);
  float* ATTNI = (float*)take((size_t)LQ_VIT * 768 * 4);
  unsigned short* VLN  = (unsigned short*)take((size_t)LQ_VIT * 768 * 2);
  float* VEXT  = (float*)take((size_t)LQ_VIT * 768 * 4);
  unsigned short* SAMPE = ADBF;   // adapter_bf16 dead after fused big GEMM
  float* ATTN2 = CBIG;            // CBIG dead after sampler_ext

  float* out_vit = (float*)d_out;
  float* out_ada = out_vit + (size_t)LQ_VIT * 768;

  TransPack tp;
  tp.W[0] = inj_Wv; tp.WT[0] = WBIG;               tp.N[0] = 768;
  tp.W[1] = ext_Ws; tp.WT[1] = WBIG + 768 * 768;   tp.N[1] = 48;
  tp.W[2] = ext_Wa; tp.WT[2] = WBIG + 816 * 768;   tp.N[2] = 24;
  tp.W[3] = inj_Wo; tp.WT[3] = WTIO;               tp.N[3] = 768;
  tp.W[4] = ext_Wv; tp.WT[4] = WTEV;               tp.N[4] = 768;
  tp.W[5] = ext_Wo; tp.WT[5] = WTEO;               tp.N[5] = 768;
  tp.W[6] = inj_Ws; tp.WT[6] = WSAI;               tp.N[6] = 144;
  tp.W[7] = inj_Wa; tp.WT[7] = WSAI + 144 * 768;   tp.N[7] = 72;
  transpose_batch_kernel<<<dim3(24, 24, 8), dim3(32, 8), 0, stream>>>(tp);
  concat_bias_kernel<<<1, 1024, 0, stream>>>(inj_bs, inj_ba, inj_bv, ext_bs, ext_ba, BCI, BBIG);

  cast_bf16_kernel<<<9072, 256, 0, stream>>>(adapter, ADBF, (NA_ADA * 768) / 4);
  ln_bf16_kernel<<<576, 256, 0, stream>>>(vit, inj_qn_g, inj_qn_b, QLN, LQ_VIT);

  // fused: v_inj (N=768) + ext sampling offsets/logits (N=72) over adapter tokens
  gemm2_kernel<128><<<95 * 7, 256, 0, stream>>>(ADBF, WBIG, BBIG, CBIG, NA_ADA, 840, 768, 95);
  gemm2_kernel<64><<<36 * 2, 256, 0, stream>>>(QLN, WSAI, BCI, SAI, LQ_VIT, 216, 768, 36);

  sampler_inj_kernel<<<1728, 256, 0, stream>>>(ref1, SAI, CBIG, SAMPI, 840);

  gemm2_kernel<64><<<36 * 6, 256, 0, stream>>>(SAMPI, WTIO, inj_bo, ATTNI, LQ_VIT, 768, 768, 36);
  residual_ln_kernel<<<576, 256, 0, stream>>>(vit, ATTNI, inj_gamma, ext_vn_g, ext_vn_b,
                                              out_vit, VLN, LQ_VIT);

  gemm2_kernel<64><<<36 * 6, 256, 0, stream>>>(VLN, WTEV, ext_bv, VEXT, LQ_VIT, 768, 768, 36);

  sampler_ext_kernel<<<9072, 256, 0, stream>>>(ref2, CBIG + 768, 840, VEXT, SAMPE);

  gemm2_kernel<128><<<95 * 6, 256, 0, stream>>>(SAMPE, WTEO, ext_bo, ATTN2, NA_ADA, 768, 768, 95);
  add_ln_f32_kernel<<<3024, 256, 0, stream>>>(adapter, ATTN2, ext_qn_g, ext_qn_b, out_ada, NA_ADA);
}

// Round 4
// 195.585 us; speedup vs baseline: 2.2224x; 1.2991x over previous
//
#include <hip/hip_runtime.h>

// InteractionBlock (ViT-Adapter injector+extractor with MSDeformAttn) for MI355X.
// R4: 3-deep pipelined GEMM (counted vmcnt(6), raw barriers, loads in flight
// across barriers), granule-XOR LDS swizzle (both sides), bf16 intermediates.

#define LQ_VIT 2304
#define NA_ADA 12096

typedef float f32x4 __attribute__((ext_vector_type(4)));
typedef short bf16x8 __attribute__((ext_vector_type(8)));

__device__ __forceinline__ unsigned short f2bf(float f) {
  unsigned u = __builtin_bit_cast(unsigned, f);
  u += 0x7FFFu + ((u >> 16) & 1u);   // round-to-nearest-even bf16
  return (unsigned short)(u >> 16);
}
__device__ __forceinline__ float bf2f(unsigned short u) {
  return __builtin_bit_cast(float, (unsigned)u << 16);
}
__device__ __forceinline__ f32x4 ld4bf(const unsigned short* p) {
  ushort4 t = *(const ushort4*)p;
  f32x4 r; r[0] = bf2f(t.x); r[1] = bf2f(t.y); r[2] = bf2f(t.z); r[3] = bf2f(t.w);
  return r;
}

__device__ __forceinline__ void gload_lds16(const void* g, void* l) {
  __builtin_amdgcn_global_load_lds(
      (__attribute__((address_space(1))) void*)(void*)g,
      (__attribute__((address_space(3))) void*)l, 16, 0, 0);
}

#define SBAR() do { __builtin_amdgcn_sched_barrier(0); \
                    __builtin_amdgcn_s_barrier(); \
                    __builtin_amdgcn_sched_barrier(0); } while (0)

// ---------------- batched weight transpose + bf16 cast: W[768,N] -> WT[N,768] --
struct TransPack {
  const float* W[8];
  unsigned short* WT[8];
  int N[8];
};

__global__ __launch_bounds__(256) void transpose_batch_kernel(TransPack tp) {
  int z = blockIdx.z;
  const float* __restrict__ W = tp.W[z];
  unsigned short* __restrict__ WT = tp.WT[z];
  int N = tp.N[z];
  int kb = blockIdx.x * 32, nb = blockIdx.y * 32;
  if (nb >= N) return;
  __shared__ float tile[32][33];
  int tx = threadIdx.x, ty = threadIdx.y;  // blockDim = (32, 8)
  for (int i = ty; i < 32; i += 8) {
    int k = kb + i, n = nb + tx;
    tile[i][tx] = (n < N) ? W[(size_t)k * N + n] : 0.f;
  }
  __syncthreads();
  for (int i = ty; i < 32; i += 8) {
    int n = nb + i, k = kb + tx;
    if (n < N) WT[(size_t)n * 768 + k] = f2bf(tile[tx][i]);
  }
}

// ---------------- bias concats -----------------------------------------------
__global__ void concat_bias_kernel(const float* __restrict__ isv, const float* __restrict__ iav,
                                   const float* __restrict__ ibv, const float* __restrict__ esv,
                                   const float* __restrict__ eav,
                                   float* __restrict__ bci, float* __restrict__ bbig) {
  int i = threadIdx.x;  // 1024 threads
  if (i < 144) bci[i] = isv[i];
  else if (i < 216) bci[i] = iav[i - 144];
  if (i < 768) bbig[i] = ibv[i];
  else if (i < 816) bbig[i] = esv[i - 768];
  else if (i < 840) bbig[i] = eav[i - 816];
}

// ---------------- f32 -> bf16 cast -------------------------------------------
__global__ __launch_bounds__(256) void cast_bf16_kernel(
    const float* __restrict__ in, unsigned short* __restrict__ out, int n4) {
  int i = blockIdx.x * 256 + threadIdx.x;
  if (i < n4) {
    float4 v = ((const float4*)in)[i];
    ushort4 o;
    o.x = f2bf(v.x); o.y = f2bf(v.y); o.z = f2bf(v.z); o.w = f2bf(v.w);
    ((ushort4*)out)[i] = o;
  }
}

// ---------------- LayerNorm (row=768) -> bf16 out ----------------------------
__global__ __launch_bounds__(256) void ln_bf16_kernel(
    const float* __restrict__ X, const float* __restrict__ g,
    const float* __restrict__ b, unsigned short* __restrict__ out, int R) {
  int wid = blockIdx.x * 4 + (threadIdx.x >> 6);
  int lane = threadIdx.x & 63;
  if (wid >= R) return;
  const float* row = X + (size_t)wid * 768;
  float x[12]; float s = 0.f;
#pragma unroll
  for (int j = 0; j < 12; j++) { x[j] = row[lane + j * 64]; s += x[j]; }
#pragma unroll
  for (int o = 32; o >= 1; o >>= 1) s += __shfl_xor(s, o);
  float mean = s * (1.f / 768.f);
  float v = 0.f;
#pragma unroll
  for (int j = 0; j < 12; j++) { float d = x[j] - mean; v += d * d; }
#pragma unroll
  for (int o = 32; o >= 1; o >>= 1) v += __shfl_xor(v, o);
  float rs = rsqrtf(v * (1.f / 768.f) + 1e-6f);
#pragma unroll
  for (int j = 0; j < 12; j++) {
    int c = lane + j * 64;
    out[(size_t)wid * 768 + c] = f2bf((x[j] - mean) * rs * g[c] + b[c]);
  }
}

// ---------------- fused residual + LayerNorm (attn in bf16) ------------------
__global__ __launch_bounds__(256) void residual_ln_kernel(
    const float* __restrict__ vit, const unsigned short* __restrict__ attn,
    const float* __restrict__ gamma, const float* __restrict__ g,
    const float* __restrict__ b, float* __restrict__ vout,
    unsigned short* __restrict__ vln, int R) {
  int wid = blockIdx.x * 4 + (threadIdx.x >> 6);
  int lane = threadIdx.x & 63;
  if (wid >= R) return;
  const float* ra = vit + (size_t)wid * 768;
  const unsigned short* rb = attn + (size_t)wid * 768;
  float x[12]; float s = 0.f;
#pragma unroll
  for (int j = 0; j < 12; j++) {
    int c = lane + j * 64;
    x[j] = ra[c] + gamma[c] * bf2f(rb[c]);
    vout[(size_t)wid * 768 + c] = x[j];
    s += x[j];
  }
#pragma unroll
  for (int o = 32; o >= 1; o >>= 1) s += __shfl_xor(s, o);
  float mean = s * (1.f / 768.f);
  float v = 0.f;
#pragma unroll
  for (int j = 0; j < 12; j++) { float d = x[j] - mean; v += d * d; }
#pragma unroll
  for (int o = 32; o >= 1; o >>= 1) v += __shfl_xor(v, o);
  float rs = rsqrtf(v * (1.f / 768.f) + 1e-6f);
#pragma unroll
  for (int j = 0; j < 12; j++) {
    int c = lane + j * 64;
    vln[(size_t)wid * 768 + c] = f2bf((x[j] - mean) * rs * g[c] + b[c]);
  }
}

// ---------------- add + LayerNorm -> f32 out (Xb in bf16) --------------------
__global__ __launch_bounds__(256) void add_ln_f32_kernel(
    const float* __restrict__ Xa, const unsigned short* __restrict__ Xb,
    const float* __restrict__ g, const float* __restrict__ b,
    float* __restrict__ out, int R) {
  int wid = blockIdx.x * 4 + (threadIdx.x >> 6);
  int lane = threadIdx.x & 63;
  if (wid >= R) return;
  const float* ra = Xa + (size_t)wid * 768;
  const unsigned short* rb = Xb + (size_t)wid * 768;
  float x[12]; float s = 0.f;
#pragma unroll
  for (int j = 0; j < 12; j++) {
    int c = lane + j * 64;
    x[j] = ra[c] + bf2f(rb[c]); s += x[j];
  }
#pragma unroll
  for (int o = 32; o >= 1; o >>= 1) s += __shfl_xor(s, o);
  float mean = s * (1.f / 768.f);
  float v = 0.f;
#pragma unroll
  for (int j = 0; j < 12; j++) { float d = x[j] - mean; v += d * d; }
#pragma unroll
  for (int o = 32; o >= 1; o >>= 1) v += __shfl_xor(v, o);
  float rs = rsqrtf(v * (1.f / 768.f) + 1e-6f);
#pragma unroll
  for (int j = 0; j < 12; j++) {
    int c = lane + j * 64;
    out[(size_t)wid * 768 + c] = (x[j] - mean) * rs * g[c] + b[c];
  }
}

// ---------------- 3-deep pipelined bf16 MFMA GEMM ----------------------------
// C[M,N] bf16 = A[M,K]bf16 @ BT[N,K]^T + bias. BM=64, BN=128, BK=64.
// 2 LDS buffers, tile t resident / t+1 in flight / t+2 issued under compute.
// Counted s_waitcnt vmcnt(6): never drains the newest prefetch.
// Granule-XOR swizzle: LDS[r][g] holds global granule g^(r&7).
__global__ __launch_bounds__(256) void gemm3_kernel(
    const unsigned short* __restrict__ A, const unsigned short* __restrict__ BT,
    const float* __restrict__ bias, unsigned short* __restrict__ C,
    int M, int N, int K, int MT) {
  __shared__ unsigned short lds[2][(64 + 128) * 64];  // 2 x 24KB

  // bijective XCD-aware swizzle (m204)
  int nwg = gridDim.x;
  int id = blockIdx.x;
  int qq = nwg >> 3, rr = nwg & 7;
  int xcd = id & 7, idx = id >> 3;
  int wg = (xcd < rr ? xcd * (qq + 1) : rr * (qq + 1) + (xcd - rr) * qq) + idx;
  int mt = wg % MT, nt = wg / MT;
  int m0 = mt * 64, n0 = nt * 128;

  int tid = threadIdx.x;
  int w = tid >> 6, lane = tid & 63;
  int frow = lane & 15, ghi = lane >> 4;       // fragment row, granule-hi
  int l7 = lane & 7;
  int sr = lane >> 3;                          // staging row within 8-row chunk
  int sgx = ((l7 ^ (sr & 7)) * 8);             // swizzled source granule (elems)
  int gxA0 = ((ghi ^ l7) * 8);                 // read granule for kk=0
  int gxA1 = (((4 + ghi) ^ l7) * 8);           // read granule for kk=32

  f32x4 acc[4][2] = {};
  int kT = K >> 6;  // 12

  auto stage = [&](unsigned short* dst, int k0) {
#pragma unroll
    for (int i = 0; i < 6; i++) {
      int c = w * 6 + i;                       // 24 chunks: 8 A + 16 B
      if (c < 8) {
        int gm = m0 + c * 8 + sr; if (gm >= M) gm = M - 1;
        gload_lds16(&A[(size_t)gm * K + k0 + sgx], &dst[c * 512]);
      } else {
        int gn = n0 + (c - 8) * 8 + sr; if (gn >= N) gn = N - 1;
        gload_lds16(&BT[(size_t)gn * K + k0 + sgx], &dst[c * 512]);
      }
    }
  };

  unsigned short* b0 = &lds[0][0];
  unsigned short* b1 = &lds[1][0];
  stage(b0, 0);
  stage(b1, 64);
  asm volatile("s_waitcnt vmcnt(6)" ::: "memory");  // tile0 resident
  SBAR();

  for (int t = 0; t < kT; t++) {
    unsigned short* cb = (t & 1) ? b1 : b0;
    const unsigned short* As_ = cb;
    const unsigned short* Bs_ = cb + 8 * 512;
    bf16x8 af0[4], af1[4], bg0[2], bg1[2];
#pragma unroll
    for (int m = 0; m < 4; m++) {
      int r = m * 16 + frow;
      af0[m] = *(const bf16x8*)&As_[r * 64 + gxA0];
      af1[m] = *(const bf16x8*)&As_[r * 64 + gxA1];
    }
#pragma unroll
    for (int n = 0; n < 2; n++) {
      int r = w * 32 + n * 16 + frow;
      bg0[n] = *(const bf16x8*)&Bs_[r * 64 + gxA0];
      bg1[n] = *(const bf16x8*)&Bs_[r * 64 + gxA1];
    }
    asm volatile("s_waitcnt lgkmcnt(0)" ::: "memory");  // frags in regs
    __builtin_amdgcn_sched_barrier(0);
    if (t < kT - 1) SBAR();                    // all waves done reading cb
    if (t + 2 < kT) stage(cb, (t + 2) << 6);   // overwrite freed buffer
#pragma unroll
    for (int m = 0; m < 4; m++)
#pragma unroll
      for (int n = 0; n < 2; n++) {
        acc[m][n] = __builtin_amdgcn_mfma_f32_16x16x32_bf16(af0[m], bg0[n], acc[m][n], 0, 0, 0);
        acc[m][n] = __builtin_amdgcn_mfma_f32_16x16x32_bf16(af1[m], bg1[n], acc[m][n], 0, 0, 0);
      }
    if (t < kT - 1) {
      if (t + 2 < kT) asm volatile("s_waitcnt vmcnt(6)" ::: "memory");  // t+1 done
      else            asm volatile("s_waitcnt vmcnt(0)" ::: "memory");
      SBAR();                                   // tile t+1 resident for all
    }
  }

  int orow = (lane >> 4) * 4, ocol = lane & 15;
#pragma unroll
  for (int m = 0; m < 4; m++) {
    int gmb = m0 + m * 16 + orow;
#pragma unroll
    for (int n = 0; n < 2; n++) {
      int gn = n0 + w * 32 + n * 16 + ocol;
      if (gn < N) {
        float bv = bias[gn];
#pragma unroll
        for (int r = 0; r < 4; r++) {
          int gm = gmb + r;
          if (gm < M) C[(size_t)gm * N + gn] = f2bf(acc[m][n][r] + bv);
        }
      }
    }
  }
}

// ---------------- deformable samplers (bf16 value/param tensors) -------------
// One wave = (query, 2 heads); lanes 0-31 head h0, 32-63 head h1; 4 ch/lane.

// Injector: Lq=2304, 6 heads, 3 levels {96,48,24}, 4 points. v stride vst.
__global__ __launch_bounds__(256) void sampler_inj_kernel(
    const float* __restrict__ ref, const unsigned short* __restrict__ sa,
    const unsigned short* __restrict__ v, unsigned short* __restrict__ out, int vst) {
  int gw = (blockIdx.x * 256 + threadIdx.x) >> 6;
  int lane = threadIdx.x & 63;
  int q = gw / 3, hp = gw - q * 3;
  if (q >= LQ_VIT) return;
  int h = hp * 2 + (lane >> 5);
  int c = h * 128 + (lane & 31) * 4;
  float rx = ref[q * 2], ry = ref[q * 2 + 1];
  const unsigned short* row = sa + (size_t)q * 216;
  float lg[12]; float mx = -1e30f;
#pragma unroll
  for (int i = 0; i < 12; i++) { lg[i] = bf2f(row[144 + h * 12 + i]); mx = fmaxf(mx, lg[i]); }
  float s = 0.f;
#pragma unroll
  for (int i = 0; i < 12; i++) { lg[i] = __expf(lg[i] - mx); s += lg[i]; }
  float inv = 1.f / s;
  f32x4 acc = {0.f, 0.f, 0.f, 0.f};
  const int LW[3] = {96, 48, 24};
  const int LS[3] = {0, 9216, 11520};
#pragma unroll
  for (int l = 0; l < 3; l++) {
    const int Wl = LW[l], st = LS[l], Wm = Wl - 1;
    const float Wf = (float)Wl;
#pragma unroll
    for (int p = 0; p < 4; p++) {
      int ob = ((h * 3 + l) * 4 + p) * 2;
      float ix = fmaf(rx, Wf, bf2f(row[ob])) - 0.5f;
      float iy = fmaf(ry, Wf, bf2f(row[ob + 1])) - 0.5f;
      float x0f = floorf(ix), y0f = floorf(iy);
      float wx = ix - x0f, wy = iy - y0f;
      int x0 = (int)x0f, y0 = (int)y0f;
      float aw = lg[l * 4 + p] * inv;
      float wy0 = (1.f - wy) * aw, wy1 = wy * aw;
      float w00 = (1.f - wx) * wy0, w01 = wx * wy0;
      float w10 = (1.f - wx) * wy1, w11 = wx * wy1;
      bool xv0 = (unsigned)x0 < (unsigned)Wl, xv1 = (unsigned)(x0 + 1) < (unsigned)Wl;
      bool yv0 = (unsigned)y0 < (unsigned)Wl, yv1 = (unsigned)(y0 + 1) < (unsigned)Wl;
      w00 = (xv0 && yv0) ? w00 : 0.f;
      w01 = (xv1 && yv0) ? w01 : 0.f;
      w10 = (xv0 && yv1) ? w10 : 0.f;
      w11 = (xv1 && yv1) ? w11 : 0.f;
      int x0c = min(max(x0, 0), Wm), x1c = min(max(x0 + 1, 0), Wm);
      int y0c = min(max(y0, 0), Wm), y1c = min(max(y0 + 1, 0), Wm);
      const unsigned short* r0 = v + ((size_t)(st + y0c * Wl) * vst + c);
      const unsigned short* r1 = v + ((size_t)(st + y1c * Wl) * vst + c);
      acc += w00 * ld4bf(r0 + (size_t)x0c * vst) + w01 * ld4bf(r0 + (size_t)x1c * vst)
           + w10 * ld4bf(r1 + (size_t)x0c * vst) + w11 * ld4bf(r1 + (size_t)x1c * vst);
    }
  }
  ushort4 o4;
  o4.x = f2bf(acc[0]); o4.y = f2bf(acc[1]); o4.z = f2bf(acc[2]); o4.w = f2bf(acc[3]);
  *(ushort4*)&out[(size_t)q * 768 + c] = o4;
}

// Extractor: Lq=12096, 6 heads, 1 level (48x48), 4 points. sa stride sst.
__global__ __launch_bounds__(256) void sampler_ext_kernel(
    const float* __restrict__ ref, const unsigned short* __restrict__ sa, int sst,
    const unsigned short* __restrict__ v, unsigned short* __restrict__ out) {
  int gw = (blockIdx.x * 256 + threadIdx.x) >> 6;
  int lane = threadIdx.x & 63;
  int q = gw / 3, hp = gw - q * 3;
  if (q >= NA_ADA) return;
  int h = hp * 2 + (lane >> 5);
  int c = h * 128 + (lane & 31) * 4;
  float rx = ref[q * 2], ry = ref[q * 2 + 1];
  const unsigned short* row = sa + (size_t)q * sst;
  float lg[4]; float mx = -1e30f;
#pragma unroll
  for (int p = 0; p < 4; p++) { lg[p] = bf2f(row[48 + h * 4 + p]); mx = fmaxf(mx, lg[p]); }
  float s = 0.f;
#pragma unroll
  for (int p = 0; p < 4; p++) { lg[p] = __expf(lg[p] - mx); s += lg[p]; }
  float inv = 1.f / s;
  f32x4 acc = {0.f, 0.f, 0.f, 0.f};
#pragma unroll
  for (int p = 0; p < 4; p++) {
    int ob = (h * 4 + p) * 2;
    float ix = fmaf(rx, 48.f, bf2f(row[ob])) - 0.5f;
    float iy = fmaf(ry, 48.f, bf2f(row[ob + 1])) - 0.5f;
    float x0f = floorf(ix), y0f = floorf(iy);
    float wx = ix - x0f, wy = iy - y0f;
    int x0 = (int)x0f, y0 = (int)y0f;
    float aw = lg[p] * inv;
    float wy0 = (1.f - wy) * aw, wy1 = wy * aw;
    float w00 = (1.f - wx) * wy0, w01 = wx * wy0;
    float w10 = (1.f - wx) * wy1, w11 = wx * wy1;
    bool xv0 = (unsigned)x0 < 48u, xv1 = (unsigned)(x0 + 1) < 48u;
    bool yv0 = (unsigned)y0 < 48u, yv1 = (unsigned)(y0 + 1) < 48u;
    w00 = (xv0 && yv0) ? w00 : 0.f;
    w01 = (xv1 && yv0) ? w01 : 0.f;
    w10 = (xv0 && yv1) ? w10 : 0.f;
    w11 = (xv1 && yv1) ? w11 : 0.f;
    int x0c = min(max(x0, 0), 47), x1c = min(max(x0 + 1, 0), 47);
    int y0c = min(max(y0, 0), 47), y1c = min(max(y0 + 1, 0), 47);
    const unsigned short* r0 = v + ((size_t)(y0c * 48) * 768 + c);
    const unsigned short* r1 = v + ((size_t)(y1c * 48) * 768 + c);
    acc += w00 * ld4bf(r0 + (size_t)x0c * 768) + w01 * ld4bf(r0 + (size_t)x1c * 768)
         + w10 * ld4bf(r1 + (size_t)x0c * 768) + w11 * ld4bf(r1 + (size_t)x1c * 768);
  }
  ushort4 o4;
  o4.x = f2bf(acc[0]); o4.y = f2bf(acc[1]); o4.z = f2bf(acc[2]); o4.w = f2bf(acc[3]);
  *(ushort4*)&out[(size_t)q * 768 + c] = o4;
}

extern "C" void kernel_launch(void* const* d_in, const int* in_sizes, int n_in,
                              void* d_out, int out_size, void* d_ws, size_t ws_size,
                              hipStream_t stream) {
  (void)in_sizes; (void)n_in; (void)out_size; (void)ws_size;
  const float* vit      = (const float*)d_in[0];
  const float* adapter  = (const float*)d_in[1];
  const float* ref1     = (const float*)d_in[2];
  const float* ref2     = (const float*)d_in[3];
  const float* inj_qn_g = (const float*)d_in[4];
  const float* inj_qn_b = (const float*)d_in[5];
  const float* inj_Wv   = (const float*)d_in[6];
  const float* inj_bv   = (const float*)d_in[7];
  const float* inj_Ws   = (const float*)d_in[8];
  const float* inj_bs   = (const float*)d_in[9];
  const float* inj_Wa   = (const float*)d_in[10];
  const float* inj_ba   = (const float*)d_in[11];
  const float* inj_Wo   = (const float*)d_in[12];
  const float* inj_bo   = (const float*)d_in[13];
  const float* inj_gamma= (const float*)d_in[14];
  const float* ext_vn_g = (const float*)d_in[15];
  const float* ext_vn_b = (const float*)d_in[16];
  const float* ext_qn_g = (const float*)d_in[17];
  const float* ext_qn_b = (const float*)d_in[18];
  const float* ext_Wv   = (const float*)d_in[19];
  const float* ext_bv   = (const float*)d_in[20];
  const float* ext_Ws   = (const float*)d_in[21];
  const float* ext_bs   = (const float*)d_in[22];
  const float* ext_Wa   = (const float*)d_in[23];
  const float* ext_ba   = (const float*)d_in[24];
  const float* ext_Wo   = (const float*)d_in[25];
  const float* ext_bo   = (const float*)d_in[26];

  size_t cur = 0;
  auto take = [&](size_t bytes) {
    void* p = (char*)d_ws + cur;
    cur += (bytes + 255) & ~(size_t)255;
    return p;
  };
  unsigned short* WBIG = (unsigned short*)take((size_t)840 * 768 * 2);
  unsigned short* WTIO = (unsigned short*)take((size_t)768 * 768 * 2);
  unsigned short* WTEV = (unsigned short*)take((size_t)768 * 768 * 2);
  unsigned short* WTEO = (unsigned short*)take((size_t)768 * 768 * 2);
  unsigned short* WSAI = (unsigned short*)take((size_t)216 * 768 * 2);
  float* BCI  = (float*)take((size_t)216 * 4);
  float* BBIG = (float*)take((size_t)840 * 4);
  unsigned short* ADBF = (unsigned short*)take((size_t)NA_ADA * 768 * 2);
  unsigned short* QLN  = (unsigned short*)take((size_t)LQ_VIT * 768 * 2);
  unsigned short* CBIG = (unsigned short*)take((size_t)NA_ADA * 840 * 2);  // [v_inj | sae]
  unsigned short* SAI  = (unsigned short*)take((size_t)LQ_VIT * 216 * 2);
  unsigned short* SAMPI= (unsigned short*)take((size_t)LQ_VIT * 768 * 2);
  unsigned short* ATTNI= (unsigned short*)take((size_t)LQ_VIT * 768 * 2);
  unsigned short* VLN  = (unsigned short*)take((size_t)LQ_VIT * 768 * 2);
  unsigned short* VEXT = (unsigned short*)take((size_t)LQ_VIT * 768 * 2);
  unsigned short* SAMPE = ADBF;   // adapter_bf16 dead after fused big GEMM
  unsigned short* ATTN2 = CBIG;   // CBIG dead after sampler_ext

  float* out_vit = (float*)d_out;
  float* out_ada = out_vit + (size_t)LQ_VIT * 768;

  TransPack tp;
  tp.W[0] = inj_Wv; tp.WT[0] = WBIG;               tp.N[0] = 768;
  tp.W[1] = ext_Ws; tp.WT[1] = WBIG + 768 * 768;   tp.N[1] = 48;
  tp.W[2] = ext_Wa; tp.WT[2] = WBIG + 816 * 768;   tp.N[2] = 24;
  tp.W[3] = inj_Wo; tp.WT[3] = WTIO;               tp.N[3] = 768;
  tp.W[4] = ext_Wv; tp.WT[4] = WTEV;               tp.N[4] = 768;
  tp.W[5] = ext_Wo; tp.WT[5] = WTEO;               tp.N[5] = 768;
  tp.W[6] = inj_Ws; tp.WT[6] = WSAI;               tp.N[6] = 144;
  tp.W[7] = inj_Wa; tp.WT[7] = WSAI + 144 * 768;   tp.N[7] = 72;
  transpose_batch_kernel<<<dim3(24, 24, 8), dim3(32, 8), 0, stream>>>(tp);
  concat_bias_kernel<<<1, 1024, 0, stream>>>(inj_bs, inj_ba, inj_bv, ext_bs, ext_ba, BCI, BBIG);

  cast_bf16_kernel<<<9072, 256, 0, stream>>>(adapter, ADBF, (NA_ADA * 768) / 4);
  ln_bf16_kernel<<<576, 256, 0, stream>>>(vit, inj_qn_g, inj_qn_b, QLN, LQ_VIT);

  // fused: v_inj (N=768) + ext sampling offsets/logits (N=72)
  gemm3_kernel<<<189 * 7, 256, 0, stream>>>(ADBF, WBIG, BBIG, CBIG, NA_ADA, 840, 768, 189);
  gemm3_kernel<<<36 * 2, 256, 0, stream>>>(QLN, WSAI, BCI, SAI, LQ_VIT, 216, 768, 36);

  sampler_inj_kernel<<<1728, 256, 0, stream>>>(ref1, SAI, CBIG, SAMPI, 840);

  gemm3_kernel<<<36 * 6, 256, 0, stream>>>(SAMPI, WTIO, inj_bo, ATTNI, LQ_VIT, 768, 768, 36);
  residual_ln_kernel<<<576, 256, 0, stream>>>(vit, ATTNI, inj_gamma, ext_vn_g, ext_vn_b,
                                              out_vit, VLN, LQ_VIT);

  gemm3_kernel<<<36 * 6, 256, 0, stream>>>(VLN, WTEV, ext_bv, VEXT, LQ_VIT, 768, 768, 36);

  sampler_ext_kernel<<<9072, 256, 0, stream>>>(ref2, CBIG + 768, 840, VEXT, SAMPE);

  gemm3_kernel<<<189 * 6, 256, 0, stream>>>(SAMPE, WTEO, ext_bo, ATTN2, NA_ADA, 768, 768, 189);
  add_ln_f32_kernel<<<3024, 256, 0, stream>>>(adapter, ATTN2, ext_qn_g, ext_qn_b, out_ada, NA_ADA);
}

// Round 5
// 180.053 us; speedup vs baseline: 2.4141x; 1.0863x over previous
//
#include <hip/hip_runtime.h>

// InteractionBlock (ViT-Adapter injector+extractor with MSDeformAttn) for MI355X.
// R5: BM=128 big GEMM (32 MFMA : 16 ds_read per wave/K-step), nt-major block
// order for L2 residency, dual-task GEMM pack, fused prep kernel. 9 launches.

#define LQ_VIT 2304
#define NA_ADA 12096

typedef float f32x4 __attribute__((ext_vector_type(4)));
typedef short bf16x8 __attribute__((ext_vector_type(8)));

__device__ __forceinline__ unsigned short f2bf(float f) {
  unsigned u = __builtin_bit_cast(unsigned, f);
  u += 0x7FFFu + ((u >> 16) & 1u);   // round-to-nearest-even bf16
  return (unsigned short)(u >> 16);
}
__device__ __forceinline__ float bf2f(unsigned short u) {
  return __builtin_bit_cast(float, (unsigned)u << 16);
}
__device__ __forceinline__ f32x4 ld4bf(const unsigned short* p) {
  ushort4 t = *(const ushort4*)p;
  f32x4 r; r[0] = bf2f(t.x); r[1] = bf2f(t.y); r[2] = bf2f(t.z); r[3] = bf2f(t.w);
  return r;
}

__device__ __forceinline__ void gload_lds16(const void* g, void* l) {
  __builtin_amdgcn_global_load_lds(
      (__attribute__((address_space(1))) void*)(void*)g,
      (__attribute__((address_space(3))) void*)l, 16, 0, 0);
}

#define SBAR() do { __builtin_amdgcn_sched_barrier(0); \
                    __builtin_amdgcn_s_barrier(); \
                    __builtin_amdgcn_sched_barrier(0); } while (0)
#define WAITV(n) do { asm volatile("s_waitcnt vmcnt(" #n ")" ::: "memory"); \
                      __builtin_amdgcn_sched_barrier(0); } while (0)

// ================= fused prep kernel =========================================
// block ranges: [0,2568) weight transpose+cast; [2568,4616) adapter cast;
// [4616,5192) vit LN; [5192] bias concat.
struct PrepPack {
  const float* W[8];
  unsigned short* WT[8];
  int N[8];
  int cum[9];  // cumulative nb (N/32 tiles)
  const float* adapter; unsigned short* adbf; int n4;
  const float* vit; const float* qg; const float* qb; unsigned short* qln;
  const float* isv; const float* iav; const float* ibv;
  const float* esv; const float* eav;
  float* bci; float* bbig;
};

__global__ __launch_bounds__(256) void prep_kernel(PrepPack pp) {
  int b = blockIdx.x;
  int tid = threadIdx.x;
  if (b < 2568) {  // ---- transpose: W[768,N] f32 -> WT[N,768] bf16
    int kb = b / 107, col = b % 107;
    int z = 0;
#pragma unroll
    for (int i = 0; i < 8; i++) if (col >= pp.cum[i + 1]) z = i + 1;
    int nb = col - pp.cum[z];
    const float* __restrict__ W = pp.W[z];
    unsigned short* __restrict__ WT = pp.WT[z];
    int N = pp.N[z];
    int kb32 = kb * 32, nb32 = nb * 32;
    __shared__ float tile[32][33];
    int tx = tid & 31, ty = tid >> 5;  // 8 rows stride
    for (int i = ty; i < 32; i += 8) {
      int n = nb32 + tx;
      tile[i][tx] = (n < N) ? W[(size_t)(kb32 + i) * N + n] : 0.f;
    }
    __syncthreads();
    for (int i = ty; i < 32; i += 8) {
      int n = nb32 + i, k = kb32 + tx;
      if (n < N) WT[(size_t)n * 768 + k] = f2bf(tile[tx][i]);
    }
  } else if (b < 4616) {  // ---- adapter f32 -> bf16 (grid-stride float4)
    for (int i = (b - 2568) * 256 + tid; i < pp.n4; i += 2048 * 256) {
      float4 v = ((const float4*)pp.adapter)[i];
      ushort4 o;
      o.x = f2bf(v.x); o.y = f2bf(v.y); o.z = f2bf(v.z); o.w = f2bf(v.w);
      ((ushort4*)pp.adbf)[i] = o;
    }
  } else if (b < 5192) {  // ---- vit LN -> bf16
    int wid = (b - 4616) * 4 + (tid >> 6);
    int lane = tid & 63;
    if (wid >= LQ_VIT) return;
    const float* row = pp.vit + (size_t)wid * 768;
    float x[12]; float s = 0.f;
#pragma unroll
    for (int j = 0; j < 12; j++) { x[j] = row[lane + j * 64]; s += x[j]; }
#pragma unroll
    for (int o = 32; o >= 1; o >>= 1) s += __shfl_xor(s, o);
    float mean = s * (1.f / 768.f);
    float v = 0.f;
#pragma unroll
    for (int j = 0; j < 12; j++) { float d = x[j] - mean; v += d * d; }
#pragma unroll
    for (int o = 32; o >= 1; o >>= 1) v += __shfl_xor(v, o);
    float rs = rsqrtf(v * (1.f / 768.f) + 1e-6f);
#pragma unroll
    for (int j = 0; j < 12; j++) {
      int c = lane + j * 64;
      pp.qln[(size_t)wid * 768 + c] = f2bf((x[j] - mean) * rs * pp.qg[c] + pp.qb[c]);
    }
  } else {  // ---- bias concat
    for (int i = tid; i < 840; i += 256) {
      if (i < 144) pp.bci[i] = pp.isv[i];
      else if (i < 216) pp.bci[i] = pp.iav[i - 144];
      if (i < 768) pp.bbig[i] = pp.ibv[i];
      else if (i < 816) pp.bbig[i] = pp.esv[i - 768];
      else pp.bbig[i] = pp.eav[i - 816];
    }
  }
}

// ================= big GEMM: BM=128, BN=128, BK=64, 3-deep pipeline ==========
// C[M,N] bf16 = A[M,K]bf16 @ BT[N,K]^T + bias. 4 waves, 64x64/wave (FM=FN=4).
// nt-major block order; bijective XCD swizzle per task; dual-task grid pack.
struct GemmTask {
  const unsigned short* A; const unsigned short* BT;
  const float* bias; unsigned short* C;
  int M, N, NT, nwg;
};

__global__ __launch_bounds__(256, 2) void gemm_big_kernel(GemmTask t0, GemmTask t1, int split) {
  __shared__ unsigned short lds[2][(128 + 128) * 64];  // 2 x 32KB

  GemmTask tk = (blockIdx.x < split) ? t0 : t1;
  int id = (blockIdx.x < split) ? blockIdx.x : blockIdx.x - split;
  // bijective XCD swizzle over this task's nwg
  int nwg = tk.nwg;
  int qq = nwg >> 3, rr = nwg & 7;
  int xcd = id & 7, idx = id >> 3;
  int wg = (xcd < rr ? xcd * (qq + 1) : rr * (qq + 1) + (xcd - rr) * qq) + idx;
  int nt = wg % tk.NT, mt = wg / tk.NT;     // nt-major: A-tile reused across nt
  int m0 = mt * 128, n0 = nt * 128;
  int M = tk.M, N = tk.N;
  const unsigned short* __restrict__ A = tk.A;
  const unsigned short* __restrict__ BT = tk.BT;
  const int K = 768, kT = 12;

  int tid = threadIdx.x;
  int w = tid >> 6, lane = tid & 63;
  int wr = w >> 1, wc = w & 1;
  int frow = lane & 15, ghi = lane >> 4;
  int l7 = lane & 7;
  int sr = lane >> 3;
  int sgx = ((l7 ^ sr) * 8);            // staging source granule (elems)
  int gx0 = ((ghi ^ l7) * 8);           // read granule kk=0
  int gx1 = (((4 + ghi) ^ l7) * 8);     // read granule kk=32

  f32x4 acc[4][4] = {};

  auto stage = [&](unsigned short* dst, int k0) {
#pragma unroll
    for (int i = 0; i < 8; i++) {
      int c = w * 8 + i;                // 32 chunks: 16 A + 16 B, 1KB each
      if (c < 16) {
        int gm = m0 + c * 8 + sr; if (gm >= M) gm = M - 1;
        gload_lds16(&A[(size_t)gm * K + k0 + sgx], &dst[c * 512]);
      } else {
        int gn = n0 + (c - 16) * 8 + sr; if (gn >= N) gn = N - 1;
        gload_lds16(&BT[(size_t)gn * K + k0 + sgx], &dst[c * 512]);
      }
    }
  };

  unsigned short* b0 = &lds[0][0];
  unsigned short* b1 = &lds[1][0];
  stage(b0, 0);
  stage(b1, 64);
  WAITV(8);   // tile 0 resident (t1's 8 in flight)
  SBAR();

  for (int t = 0; t < kT; t++) {
    unsigned short* cb = (t & 1) ? b1 : b0;
    const unsigned short* As_ = cb;
    const unsigned short* Bs_ = cb + 16 * 512;
    bf16x8 af0[4], af1[4], bg0[4], bg1[4];
#pragma unroll
    for (int m = 0; m < 4; m++) {
      int r = wr * 64 + m * 16 + frow;
      af0[m] = *(const bf16x8*)&As_[r * 64 + gx0];
      af1[m] = *(const bf16x8*)&As_[r * 64 + gx1];
    }
#pragma unroll
    for (int n = 0; n < 4; n++) {
      int r = wc * 64 + n * 16 + frow;
      bg0[n] = *(const bf16x8*)&Bs_[r * 64 + gx0];
      bg1[n] = *(const bf16x8*)&Bs_[r * 64 + gx1];
    }
    asm volatile("s_waitcnt lgkmcnt(0)" ::: "memory");
    __builtin_amdgcn_sched_barrier(0);
    if (t < kT - 1) SBAR();                  // all waves done reading cb
    if (t + 2 < kT) stage(cb, (t + 2) << 6); // overwrite freed buffer
#pragma unroll
    for (int m = 0; m < 4; m++)
#pragma unroll
      for (int n = 0; n < 4; n++) {
        acc[m][n] = __builtin_amdgcn_mfma_f32_16x16x32_bf16(af0[m], bg0[n], acc[m][n], 0, 0, 0);
        acc[m][n] = __builtin_amdgcn_mfma_f32_16x16x32_bf16(af1[m], bg1[n], acc[m][n], 0, 0, 0);
      }
    if (t < kT - 1) {
      if (t + 2 < kT) WAITV(8);   // tile t+1 landed; t+2 stays in flight
      else            WAITV(0);
      SBAR();
    }
  }

  int orow = (lane >> 4) * 4, ocol = lane & 15;
  unsigned short* C = tk.C;
  const float* bias = tk.bias;
#pragma unroll
  for (int m = 0; m < 4; m++) {
    int gmb = m0 + wr * 64 + m * 16 + orow;
#pragma unroll
    for (int n = 0; n < 4; n++) {
      int gn = n0 + wc * 64 + n * 16 + ocol;
      if (gn < N) {
        float bv = bias[gn];
#pragma unroll
        for (int r = 0; r < 4; r++) {
          int gm = gmb + r;
          if (gm < M) C[(size_t)gm * N + gn] = f2bf(acc[m][n][r] + bv);
        }
      }
    }
  }
}

// ================= mid GEMM: BM=64, BN=128, 3-deep pipeline ==================
__global__ __launch_bounds__(256) void gemm_mid_kernel(
    const unsigned short* __restrict__ A, const unsigned short* __restrict__ BT,
    const float* __restrict__ bias, unsigned short* __restrict__ C,
    int M, int N, int NT) {
  __shared__ unsigned short lds[2][(64 + 128) * 64];  // 2 x 24KB

  int nwg = gridDim.x;
  int id = blockIdx.x;
  int qq = nwg >> 3, rr = nwg & 7;
  int xcd = id & 7, idx = id >> 3;
  int wg = (xcd < rr ? xcd * (qq + 1) : rr * (qq + 1) + (xcd - rr) * qq) + idx;
  int nt = wg % NT, mt = wg / NT;
  int m0 = mt * 64, n0 = nt * 128;
  const int K = 768, kT = 12;

  int tid = threadIdx.x;
  int w = tid >> 6, lane = tid & 63;
  int frow = lane & 15, ghi = lane >> 4;
  int l7 = lane & 7;
  int sr = lane >> 3;
  int sgx = ((l7 ^ sr) * 8);
  int gx0 = ((ghi ^ l7) * 8);
  int gx1 = (((4 + ghi) ^ l7) * 8);

  f32x4 acc[4][2] = {};

  auto stage = [&](unsigned short* dst, int k0) {
#pragma unroll
    for (int i = 0; i < 6; i++) {
      int c = w * 6 + i;                // 24 chunks: 8 A + 16 B
      if (c < 8) {
        int gm = m0 + c * 8 + sr; if (gm >= M) gm = M - 1;
        gload_lds16(&A[(size_t)gm * K + k0 + sgx], &dst[c * 512]);
      } else {
        int gn = n0 + (c - 8) * 8 + sr; if (gn >= N) gn = N - 1;
        gload_lds16(&BT[(size_t)gn * K + k0 + sgx], &dst[c * 512]);
      }
    }
  };

  unsigned short* b0 = &lds[0][0];
  unsigned short* b1 = &lds[1][0];
  stage(b0, 0);
  stage(b1, 64);
  WAITV(6);
  SBAR();

  for (int t = 0; t < kT; t++) {
    unsigned short* cb = (t & 1) ? b1 : b0;
    const unsigned short* As_ = cb;
    const unsigned short* Bs_ = cb + 8 * 512;
    bf16x8 af0[4], af1[4], bg0[2], bg1[2];
#pragma unroll
    for (int m = 0; m < 4; m++) {
      int r = m * 16 + frow;
      af0[m] = *(const bf16x8*)&As_[r * 64 + gx0];
      af1[m] = *(const bf16x8*)&As_[r * 64 + gx1];
    }
#pragma unroll
    for (int n = 0; n < 2; n++) {
      int r = w * 32 + n * 16 + frow;
      bg0[n] = *(const bf16x8*)&Bs_[r * 64 + gx0];
      bg1[n] = *(const bf16x8*)&Bs_[r * 64 + gx1];
    }
    asm volatile("s_waitcnt lgkmcnt(0)" ::: "memory");
    __builtin_amdgcn_sched_barrier(0);
    if (t < kT - 1) SBAR();
    if (t + 2 < kT) stage(cb, (t + 2) << 6);
#pragma unroll
    for (int m = 0; m < 4; m++)
#pragma unroll
      for (int n = 0; n < 2; n++) {
        acc[m][n] = __builtin_amdgcn_mfma_f32_16x16x32_bf16(af0[m], bg0[n], acc[m][n], 0, 0, 0);
        acc[m][n] = __builtin_amdgcn_mfma_f32_16x16x32_bf16(af1[m], bg1[n], acc[m][n], 0, 0, 0);
      }
    if (t < kT - 1) {
      if (t + 2 < kT) WAITV(6);
      else            WAITV(0);
      SBAR();
    }
  }

  int orow = (lane >> 4) * 4, ocol = lane & 15;
#pragma unroll
  for (int m = 0; m < 4; m++) {
    int gmb = m0 + m * 16 + orow;
#pragma unroll
    for (int n = 0; n < 2; n++) {
      int gn = n0 + w * 32 + n * 16 + ocol;
      if (gn < N) {
        float bv = bias[gn];
#pragma unroll
        for (int r = 0; r < 4; r++) {
          int gm = gmb + r;
          if (gm < M) C[(size_t)gm * N + gn] = f2bf(acc[m][n][r] + bv);
        }
      }
    }
  }
}

// ---------------- fused residual + LayerNorm (attn in bf16) ------------------
__global__ __launch_bounds__(256) void residual_ln_kernel(
    const float* __restrict__ vit, const unsigned short* __restrict__ attn,
    const float* __restrict__ gamma, const float* __restrict__ g,
    const float* __restrict__ b, float* __restrict__ vout,
    unsigned short* __restrict__ vln, int R) {
  int wid = blockIdx.x * 4 + (threadIdx.x >> 6);
  int lane = threadIdx.x & 63;
  if (wid >= R) return;
  const float* ra = vit + (size_t)wid * 768;
  const unsigned short* rb = attn + (size_t)wid * 768;
  float x[12]; float s = 0.f;
#pragma unroll
  for (int j = 0; j < 12; j++) {
    int c = lane + j * 64;
    x[j] = ra[c] + gamma[c] * bf2f(rb[c]);
    vout[(size_t)wid * 768 + c] = x[j];
    s += x[j];
  }
#pragma unroll
  for (int o = 32; o >= 1; o >>= 1) s += __shfl_xor(s, o);
  float mean = s * (1.f / 768.f);
  float v = 0.f;
#pragma unroll
  for (int j = 0; j < 12; j++) { float d = x[j] - mean; v += d * d; }
#pragma unroll
  for (int o = 32; o >= 1; o >>= 1) v += __shfl_xor(v, o);
  float rs = rsqrtf(v * (1.f / 768.f) + 1e-6f);
#pragma unroll
  for (int j = 0; j < 12; j++) {
    int c = lane + j * 64;
    vln[(size_t)wid * 768 + c] = f2bf((x[j] - mean) * rs * g[c] + b[c]);
  }
}

// ---------------- add + LayerNorm -> f32 out (Xb in bf16) --------------------
__global__ __launch_bounds__(256) void add_ln_f32_kernel(
    const float* __restrict__ Xa, const unsigned short* __restrict__ Xb,
    const float* __restrict__ g, const float* __restrict__ b,
    float* __restrict__ out, int R) {
  int wid = blockIdx.x * 4 + (threadIdx.x >> 6);
  int lane = threadIdx.x & 63;
  if (wid >= R) return;
  const float* ra = Xa + (size_t)wid * 768;
  const unsigned short* rb = Xb + (size_t)wid * 768;
  float x[12]; float s = 0.f;
#pragma unroll
  for (int j = 0; j < 12; j++) {
    int c = lane + j * 64;
    x[j] = ra[c] + bf2f(rb[c]); s += x[j];
  }
#pragma unroll
  for (int o = 32; o >= 1; o >>= 1) s += __shfl_xor(s, o);
  float mean = s * (1.f / 768.f);
  float v = 0.f;
#pragma unroll
  for (int j = 0; j < 12; j++) { float d = x[j] - mean; v += d * d; }
#pragma unroll
  for (int o = 32; o >= 1; o >>= 1) v += __shfl_xor(v, o);
  float rs = rsqrtf(v * (1.f / 768.f) + 1e-6f);
#pragma unroll
  for (int j = 0; j < 12; j++) {
    int c = lane + j * 64;
    out[(size_t)wid * 768 + c] = (x[j] - mean) * rs * g[c] + b[c];
  }
}

// ---------------- deformable samplers (bf16 tensors) -------------------------
__global__ __launch_bounds__(256) void sampler_inj_kernel(
    const float* __restrict__ ref, const unsigned short* __restrict__ sa,
    const unsigned short* __restrict__ v, unsigned short* __restrict__ out, int vst) {
  int gw = (blockIdx.x * 256 + threadIdx.x) >> 6;
  int lane = threadIdx.x & 63;
  int q = gw / 3, hp = gw - q * 3;
  if (q >= LQ_VIT) return;
  int h = hp * 2 + (lane >> 5);
  int c = h * 128 + (lane & 31) * 4;
  float rx = ref[q * 2], ry = ref[q * 2 + 1];
  const unsigned short* row = sa + (size_t)q * 216;
  float lg[12]; float mx = -1e30f;
#pragma unroll
  for (int i = 0; i < 12; i++) { lg[i] = bf2f(row[144 + h * 12 + i]); mx = fmaxf(mx, lg[i]); }
  float s = 0.f;
#pragma unroll
  for (int i = 0; i < 12; i++) { lg[i] = __expf(lg[i] - mx); s += lg[i]; }
  float inv = 1.f / s;
  f32x4 acc = {0.f, 0.f, 0.f, 0.f};
  const int LW[3] = {96, 48, 24};
  const int LS[3] = {0, 9216, 11520};
#pragma unroll
  for (int l = 0; l < 3; l++) {
    const int Wl = LW[l], st = LS[l], Wm = Wl - 1;
    const float Wf = (float)Wl;
#pragma unroll
    for (int p = 0; p < 4; p++) {
      int ob = ((h * 3 + l) * 4 + p) * 2;
      float ix = fmaf(rx, Wf, bf2f(row[ob])) - 0.5f;
      float iy = fmaf(ry, Wf, bf2f(row[ob + 1])) - 0.5f;
      float x0f = floorf(ix), y0f = floorf(iy);
      float wx = ix - x0f, wy = iy - y0f;
      int x0 = (int)x0f, y0 = (int)y0f;
      float aw = lg[l * 4 + p] * inv;
      float wy0 = (1.f - wy) * aw, wy1 = wy * aw;
      float w00 = (1.f - wx) * wy0, w01 = wx * wy0;
      float w10 = (1.f - wx) * wy1, w11 = wx * wy1;
      bool xv0 = (unsigned)x0 < (unsigned)Wl, xv1 = (unsigned)(x0 + 1) < (unsigned)Wl;
      bool yv0 = (unsigned)y0 < (unsigned)Wl, yv1 = (unsigned)(y0 + 1) < (unsigned)Wl;
      w00 = (xv0 && yv0) ? w00 : 0.f;
      w01 = (xv1 && yv0) ? w01 : 0.f;
      w10 = (xv0 && yv1) ? w10 : 0.f;
      w11 = (xv1 && yv1) ? w11 : 0.f;
      int x0c = min(max(x0, 0), Wm), x1c = min(max(x0 + 1, 0), Wm);
      int y0c = min(max(y0, 0), Wm), y1c = min(max(y0 + 1, 0), Wm);
      const unsigned short* r0 = v + ((size_t)(st + y0c * Wl) * vst + c);
      const unsigned short* r1 = v + ((size_t)(st + y1c * Wl) * vst + c);
      acc += w00 * ld4bf(r0 + (size_t)x0c * vst) + w01 * ld4bf(r0 + (size_t)x1c * vst)
           + w10 * ld4bf(r1 + (size_t)x0c * vst) + w11 * ld4bf(r1 + (size_t)x1c * vst);
    }
  }
  ushort4 o4;
  o4.x = f2bf(acc[0]); o4.y = f2bf(acc[1]); o4.z = f2bf(acc[2]); o4.w = f2bf(acc[3]);
  *(ushort4*)&out[(size_t)q * 768 + c] = o4;
}

__global__ __launch_bounds__(256) void sampler_ext_kernel(
    const float* __restrict__ ref, const unsigned short* __restrict__ sa, int sst,
    const unsigned short* __restrict__ v, unsigned short* __restrict__ out) {
  int gw = (blockIdx.x * 256 + threadIdx.x) >> 6;
  int lane = threadIdx.x & 63;
  int q = gw / 3, hp = gw - q * 3;
  if (q >= NA_ADA) return;
  int h = hp * 2 + (lane >> 5);
  int c = h * 128 + (lane & 31) * 4;
  float rx = ref[q * 2], ry = ref[q * 2 + 1];
  const unsigned short* row = sa + (size_t)q * sst;
  float lg[4]; float mx = -1e30f;
#pragma unroll
  for (int p = 0; p < 4; p++) { lg[p] = bf2f(row[48 + h * 4 + p]); mx = fmaxf(mx, lg[p]); }
  float s = 0.f;
#pragma unroll
  for (int p = 0; p < 4; p++) { lg[p] = __expf(lg[p] - mx); s += lg[p]; }
  float inv = 1.f / s;
  f32x4 acc = {0.f, 0.f, 0.f, 0.f};
#pragma unroll
  for (int p = 0; p < 4; p++) {
    int ob = (h * 4 + p) * 2;
    float ix = fmaf(rx, 48.f, bf2f(row[ob])) - 0.5f;
    float iy = fmaf(ry, 48.f, bf2f(row[ob + 1])) - 0.5f;
    float x0f = floorf(ix), y0f = floorf(iy);
    float wx = ix - x0f, wy = iy - y0f;
    int x0 = (int)x0f, y0 = (int)y0f;
    float aw = lg[p] * inv;
    float wy0 = (1.f - wy) * aw, wy1 = wy * aw;
    float w00 = (1.f - wx) * wy0, w01 = wx * wy0;
    float w10 = (1.f - wx) * wy1, w11 = wx * wy1;
    bool xv0 = (unsigned)x0 < 48u, xv1 = (unsigned)(x0 + 1) < 48u;
    bool yv0 = (unsigned)y0 < 48u, yv1 = (unsigned)(y0 + 1) < 48u;
    w00 = (xv0 && yv0) ? w00 : 0.f;
    w01 = (xv1 && yv0) ? w01 : 0.f;
    w10 = (xv0 && yv1) ? w10 : 0.f;
    w11 = (xv1 && yv1) ? w11 : 0.f;
    int x0c = min(max(x0, 0), 47), x1c = min(max(x0 + 1, 0), 47);
    int y0c = min(max(y0, 0), 47), y1c = min(max(y0 + 1, 0), 47);
    const unsigned short* r0 = v + ((size_t)(y0c * 48) * 768 + c);
    const unsigned short* r1 = v + ((size_t)(y1c * 48) * 768 + c);
    acc += w00 * ld4bf(r0 + (size_t)x0c * 768) + w01 * ld4bf(r0 + (size_t)x1c * 768)
         + w10 * ld4bf(r1 + (size_t)x0c * 768) + w11 * ld4bf(r1 + (size_t)x1c * 768);
  }
  ushort4 o4;
  o4.x = f2bf(acc[0]); o4.y = f2bf(acc[1]); o4.z = f2bf(acc[2]); o4.w = f2bf(acc[3]);
  *(ushort4*)&out[(size_t)q * 768 + c] = o4;
}

extern "C" void kernel_launch(void* const* d_in, const int* in_sizes, int n_in,
                              void* d_out, int out_size, void* d_ws, size_t ws_size,
                              hipStream_t stream) {
  (void)in_sizes; (void)n_in; (void)out_size; (void)ws_size;
  const float* vit      = (const float*)d_in[0];
  const float* adapter  = (const float*)d_in[1];
  const float* ref1     = (const float*)d_in[2];
  const float* ref2     = (const float*)d_in[3];
  const float* inj_qn_g = (const float*)d_in[4];
  const float* inj_qn_b = (const float*)d_in[5];
  const float* inj_Wv   = (const float*)d_in[6];
  const float* inj_bv   = (const float*)d_in[7];
  const float* inj_Ws   = (const float*)d_in[8];
  const float* inj_bs   = (const float*)d_in[9];
  const float* inj_Wa   = (const float*)d_in[10];
  const float* inj_ba   = (const float*)d_in[11];
  const float* inj_Wo   = (const float*)d_in[12];
  const float* inj_bo   = (const float*)d_in[13];
  const float* inj_gamma= (const float*)d_in[14];
  const float* ext_vn_g = (const float*)d_in[15];
  const float* ext_vn_b = (const float*)d_in[16];
  const float* ext_qn_g = (const float*)d_in[17];
  const float* ext_qn_b = (const float*)d_in[18];
  const float* ext_Wv   = (const float*)d_in[19];
  const float* ext_bv   = (const float*)d_in[20];
  const float* ext_Ws   = (const float*)d_in[21];
  const float* ext_bs   = (const float*)d_in[22];
  const float* ext_Wa   = (const float*)d_in[23];
  const float* ext_ba   = (const float*)d_in[24];
  const float* ext_Wo   = (const float*)d_in[25];
  const float* ext_bo   = (const float*)d_in[26];

  size_t cur = 0;
  auto take = [&](size_t bytes) {
    void* p = (char*)d_ws + cur;
    cur += (bytes + 255) & ~(size_t)255;
    return p;
  };
  unsigned short* WBIG = (unsigned short*)take((size_t)840 * 768 * 2);
  unsigned short* WTIO = (unsigned short*)take((size_t)768 * 768 * 2);
  unsigned short* WTEV = (unsigned short*)take((size_t)768 * 768 * 2);
  unsigned short* WTEO = (unsigned short*)take((size_t)768 * 768 * 2);
  unsigned short* WSAI = (unsigned short*)take((size_t)216 * 768 * 2);
  float* BCI  = (float*)take((size_t)216 * 4);
  float* BBIG = (float*)take((size_t)840 * 4);
  unsigned short* ADBF = (unsigned short*)take((size_t)NA_ADA * 768 * 2);
  unsigned short* QLN  = (unsigned short*)take((size_t)LQ_VIT * 768 * 2);
  unsigned short* CBIG = (unsigned short*)take((size_t)NA_ADA * 840 * 2);  // [v_inj | sae]
  unsigned short* SAI  = (unsigned short*)take((size_t)LQ_VIT * 216 * 2);
  unsigned short* SAMPI= (unsigned short*)take((size_t)LQ_VIT * 768 * 2);
  unsigned short* ATTNI= (unsigned short*)take((size_t)LQ_VIT * 768 * 2);
  unsigned short* VLN  = (unsigned short*)take((size_t)LQ_VIT * 768 * 2);
  unsigned short* VEXT = (unsigned short*)take((size_t)LQ_VIT * 768 * 2);
  unsigned short* SAMPE = ADBF;   // adapter_bf16 dead after big GEMM 1
  unsigned short* ATTN2 = CBIG;   // CBIG dead after sampler_ext

  float* out_vit = (float*)d_out;
  float* out_ada = out_vit + (size_t)LQ_VIT * 768;

  PrepPack pp;
  pp.W[0] = inj_Wv; pp.WT[0] = WBIG;               pp.N[0] = 768;
  pp.W[1] = ext_Ws; pp.WT[1] = WBIG + 768 * 768;   pp.N[1] = 48;
  pp.W[2] = ext_Wa; pp.WT[2] = WBIG + 816 * 768;   pp.N[2] = 24;
  pp.W[3] = inj_Wo; pp.WT[3] = WTIO;               pp.N[3] = 768;
  pp.W[4] = ext_Wv; pp.WT[4] = WTEV;               pp.N[4] = 768;
  pp.W[5] = ext_Wo; pp.WT[5] = WTEO;               pp.N[5] = 768;
  pp.W[6] = inj_Ws; pp.WT[6] = WSAI;               pp.N[6] = 144;
  pp.W[7] = inj_Wa; pp.WT[7] = WSAI + 144 * 768;   pp.N[7] = 72;
  int cum = 0;
  for (int i = 0; i < 8; i++) { pp.cum[i] = cum; cum += (pp.N[i] + 31) / 32; }
  pp.cum[8] = cum;  // 107
  pp.adapter = adapter; pp.adbf = ADBF; pp.n4 = (NA_ADA * 768) / 4;
  pp.vit = vit; pp.qg = inj_qn_g; pp.qb = inj_qn_b; pp.qln = QLN;
  pp.isv = inj_bs; pp.iav = inj_ba; pp.ibv = inj_bv;
  pp.esv = ext_bs; pp.eav = ext_ba;
  pp.bci = BCI; pp.bbig = BBIG;
  prep_kernel<<<5193, 256, 0, stream>>>(pp);

  // launch 2: big GEMM 1 (v_inj + ext S/A, N=840) packed with SAI GEMM (N=216)
  GemmTask tA, tB;
  tA.A = ADBF; tA.BT = WBIG; tA.bias = BBIG; tA.C = CBIG;
  tA.M = NA_ADA; tA.N = 840; tA.NT = 7; tA.nwg = 95 * 7;
  tB.A = QLN; tB.BT = WSAI; tB.bias = BCI; tB.C = SAI;
  tB.M = LQ_VIT; tB.N = 216; tB.NT = 2; tB.nwg = 18 * 2;
  gemm_big_kernel<<<95 * 7 + 18 * 2, 256, 0, stream>>>(tA, tB, 95 * 7);

  sampler_inj_kernel<<<1728, 256, 0, stream>>>(ref1, SAI, CBIG, SAMPI, 840);

  gemm_mid_kernel<<<36 * 6, 256, 0, stream>>>(SAMPI, WTIO, inj_bo, ATTNI, LQ_VIT, 768, 6);
  residual_ln_kernel<<<576, 256, 0, stream>>>(vit, ATTNI, inj_gamma, ext_vn_g, ext_vn_b,
                                              out_vit, VLN, LQ_VIT);
  gemm_mid_kernel<<<36 * 6, 256, 0, stream>>>(VLN, WTEV, ext_bv, VEXT, LQ_VIT, 768, 6);

  sampler_ext_kernel<<<9072, 256, 0, stream>>>(ref2, CBIG + 768, 840, VEXT, SAMPE);

  GemmTask tC;
  tC.A = SAMPE; tC.BT = WTEO; tC.bias = ext_bo; tC.C = ATTN2;
  tC.M = NA_ADA; tC.N = 768; tC.NT = 6; tC.nwg = 95 * 6;
  gemm_big_kernel<<<95 * 6, 256, 0, stream>>>(tC, tC, 95 * 6);

  add_ln_f32_kernel<<<3024, 256, 0, stream>>>(adapter, ATTN2, ext_qn_g, ext_qn_b, out_ada, NA_ADA);
}